// Round 1
// baseline (685.009 us; speedup 1.0000x reference)
//
#include <hip/hip_runtime.h>
#include <math.h>

#define N_NODES 100000
#define N_EDGES 1600000
#define N_GRAPHS 256
#define IN_F 64
#define H_F 128
#define GN_EPS 1e-5f

// ---------------- scatter-add aggregation: agg[dst] += x[src] ----------------
__global__ __launch_bounds__(256) void k_scatter(
    const float* __restrict__ x, const int* __restrict__ src,
    const int* __restrict__ dst, float* __restrict__ agg) {
  long long t = (long long)blockIdx.x * 256 + threadIdx.x;
  int e = (int)(t >> 6);
  if (e >= N_EDGES) return;
  int f = (int)(t & 63);
  int s = src[e], d = dst[e];
  unsafeAtomicAdd(&agg[(size_t)d * IN_F + f], x[(size_t)s * IN_F + f]);
}

// ---------------- GEMM1: out = relu((x+agg) @ W1 + b1), K=64 ----------------
__global__ __launch_bounds__(256) void k_gemm1(
    const float* __restrict__ xin, const float* __restrict__ agg,
    const float* __restrict__ W, const float* __restrict__ bias,
    float* __restrict__ out) {
  __shared__ float xT[IN_F][36];     // transposed x tile [k][m], stride 36 keeps 16B align
  __shared__ float Ws[IN_F * H_F];   // 32 KB
  const int t = threadIdx.x;
  const int m0 = blockIdx.x * 32;
#pragma unroll
  for (int it = 0; it < 2; ++it) {
    int flat = (t + it * 256) * 4;          // [32][64] row-major
    int m = flat >> 6, k = flat & 63;
    float4 a = *(const float4*)&xin[(size_t)(m0 + m) * IN_F + k];
    float4 g = *(const float4*)&agg[(size_t)(m0 + m) * IN_F + k];
    xT[k + 0][m] = a.x + g.x;
    xT[k + 1][m] = a.y + g.y;
    xT[k + 2][m] = a.z + g.z;
    xT[k + 3][m] = a.w + g.w;
  }
#pragma unroll
  for (int it = 0; it < 8; ++it) {
    int flat = (t + it * 256) * 4;
    *(float4*)&Ws[flat] = *(const float4*)&W[flat];
  }
  __syncthreads();
  const int tm0 = (t >> 5) * 4, tn0 = (t & 31) * 4;
  float acc[4][4] = {};
#pragma unroll 4
  for (int k = 0; k < IN_F; ++k) {
    float4 a = *(const float4*)&xT[k][tm0];
    float4 b = *(const float4*)&Ws[k * H_F + tn0];
    acc[0][0] += a.x * b.x; acc[0][1] += a.x * b.y; acc[0][2] += a.x * b.z; acc[0][3] += a.x * b.w;
    acc[1][0] += a.y * b.x; acc[1][1] += a.y * b.y; acc[1][2] += a.y * b.z; acc[1][3] += a.y * b.w;
    acc[2][0] += a.z * b.x; acc[2][1] += a.z * b.y; acc[2][2] += a.z * b.z; acc[2][3] += a.z * b.w;
    acc[3][0] += a.w * b.x; acc[3][1] += a.w * b.y; acc[3][2] += a.w * b.z; acc[3][3] += a.w * b.w;
  }
  float4 bv = *(const float4*)&bias[tn0];
#pragma unroll
  for (int i = 0; i < 4; ++i) {
    float4 r;
    r.x = fmaxf(acc[i][0] + bv.x, 0.f);
    r.y = fmaxf(acc[i][1] + bv.y, 0.f);
    r.z = fmaxf(acc[i][2] + bv.z, 0.f);
    r.w = fmaxf(acc[i][3] + bv.w, 0.f);
    *(float4*)&out[(size_t)(m0 + tm0 + i) * H_F + tn0] = r;
  }
}

// ---------------- GEMM (K=128): out = relu(in @ W + b); in-place safe ----------------
__global__ __launch_bounds__(256) void k_gemm128(
    const float* __restrict__ in, const float* __restrict__ W,
    const float* __restrict__ bias, float* __restrict__ out) {
  __shared__ float xT[H_F][36];     // 18 KB
  __shared__ float Ws[64 * H_F];    // 32 KB (half of W at a time)
  const int t = threadIdx.x;
  const int m0 = blockIdx.x * 32;
#pragma unroll
  for (int it = 0; it < 4; ++it) {
    int flat = (t + it * 256) * 4;          // [32][128] row-major
    int m = flat >> 7, k = flat & 127;
    float4 v = *(const float4*)&in[(size_t)(m0 + m) * H_F + k];
    xT[k + 0][m] = v.x; xT[k + 1][m] = v.y; xT[k + 2][m] = v.z; xT[k + 3][m] = v.w;
  }
  const int tm0 = (t >> 5) * 4, tn0 = (t & 31) * 4;
  float acc[4][4] = {};
  for (int kh = 0; kh < 2; ++kh) {
    __syncthreads();   // covers xT staging (kh=0) and Ws reuse (kh=1)
#pragma unroll
    for (int it = 0; it < 8; ++it) {
      int flat = (t + it * 256) * 4;
      *(float4*)&Ws[flat] = *(const float4*)&W[kh * 64 * H_F + flat];
    }
    __syncthreads();
#pragma unroll 4
    for (int k = 0; k < 64; ++k) {
      float4 a = *(const float4*)&xT[kh * 64 + k][tm0];
      float4 b = *(const float4*)&Ws[k * H_F + tn0];
      acc[0][0] += a.x * b.x; acc[0][1] += a.x * b.y; acc[0][2] += a.x * b.z; acc[0][3] += a.x * b.w;
      acc[1][0] += a.y * b.x; acc[1][1] += a.y * b.y; acc[1][2] += a.y * b.z; acc[1][3] += a.y * b.w;
      acc[2][0] += a.z * b.x; acc[2][1] += a.z * b.y; acc[2][2] += a.z * b.z; acc[2][3] += a.z * b.w;
      acc[3][0] += a.w * b.x; acc[3][1] += a.w * b.y; acc[3][2] += a.w * b.z; acc[3][3] += a.w * b.w;
    }
  }
  float4 bv = *(const float4*)&bias[tn0];
#pragma unroll
  for (int i = 0; i < 4; ++i) {
    float4 r;
    r.x = fmaxf(acc[i][0] + bv.x, 0.f);
    r.y = fmaxf(acc[i][1] + bv.y, 0.f);
    r.z = fmaxf(acc[i][2] + bv.z, 0.f);
    r.w = fmaxf(acc[i][3] + bv.w, 0.f);
    *(float4*)&out[(size_t)(m0 + tm0 + i) * H_F + tn0] = r;
  }
}

// ---------------- GraphNorm + ReLU + segment-max, one block per graph ----------------
__global__ __launch_bounds__(256) void k_norm(
    float* __restrict__ h, const int* __restrict__ batch,
    const float* __restrict__ gms, const float* __restrict__ gw,
    const float* __restrict__ gb, float* __restrict__ flat) {
  const int g = blockIdx.x;
  const int t = threadIdx.x;
  __shared__ int sb[2];
  __shared__ float red[2][H_F];
  __shared__ float meanS[H_F], scaleS[H_F];
  if (t < 2) {
    int target = g + t;
    int lo = 0, hi = N_NODES;
    while (lo < hi) { int mid = (lo + hi) >> 1; if (batch[mid] < target) lo = mid + 1; else hi = mid; }
    sb[t] = lo;
  }
  __syncthreads();
  const int s = sb[0], e = sb[1];
  const int cnt = e - s;
  const int f = t & 127;
  const int half = t >> 7;
  if (cnt <= 0) {
    if (t < H_F) flat[(size_t)g * H_F + t] = -INFINITY;
    return;
  }
  // pass 1: mean
  float sum = 0.f;
  for (int n = s + half; n < e; n += 2) sum += h[(size_t)n * H_F + f];
  red[half][f] = sum;
  __syncthreads();
  if (half == 0) meanS[f] = (red[0][f] + red[1][f]) / (float)cnt * gms[f];
  __syncthreads();
  const float msc = meanS[f];
  // pass 2: var
  float sq = 0.f;
  for (int n = s + half; n < e; n += 2) {
    float v = h[(size_t)n * H_F + f] - msc;
    sq += v * v;
  }
  red[half][f] = sq;
  __syncthreads();
  if (half == 0) {
    float var = (red[0][f] + red[1][f]) / (float)cnt;
    scaleS[f] = 1.0f / sqrtf(var + GN_EPS) * gw[f];
  }
  __syncthreads();
  const float sc = scaleS[f], bb = gb[f];
  // pass 3: normalize + relu + track max
  float mx = -INFINITY;
  for (int n = s + half; n < e; n += 2) {
    size_t idx = (size_t)n * H_F + f;
    float v = (h[idx] - msc) * sc + bb;
    v = fmaxf(v, 0.f);
    h[idx] = v;
    mx = fmaxf(mx, v);
  }
  red[half][f] = mx;
  __syncthreads();
  if (half == 0) flat[(size_t)g * H_F + f] = fmaxf(red[0][f], red[1][f]);
}

// ---------------- passthrough copies ----------------
__global__ __launch_bounds__(256) void k_copy_i2f(const int* __restrict__ in,
                                                  float* __restrict__ out, int n) {
  int i = blockIdx.x * 256 + threadIdx.x;
  if (i < n) out[i] = (float)in[i];
}
__global__ __launch_bounds__(256) void k_copy_f4(const float4* __restrict__ in,
                                                 float4* __restrict__ out, int n4) {
  int i = blockIdx.x * 256 + threadIdx.x;
  if (i < n4) out[i] = in[i];
}

extern "C" void kernel_launch(void* const* d_in, const int* in_sizes, int n_in,
                              void* d_out, int out_size, void* d_ws, size_t ws_size,
                              hipStream_t stream) {
  const float* inputs = (const float*)d_in[0];
  const int*   ei     = (const int*)d_in[1];   // [2, N_EDGES]
  const int*   batch  = (const int*)d_in[2];   // [N_NODES]
  const float* eattr  = (const float*)d_in[3]; // [N_EDGES, 8]
  const float* W1 = (const float*)d_in[4];
  const float* b1 = (const float*)d_in[5];
  const float* W2 = (const float*)d_in[6];
  const float* b2 = (const float*)d_in[7];
  const float* W3 = (const float*)d_in[8];
  const float* b3 = (const float*)d_in[9];
  const float* gw  = (const float*)d_in[10];
  const float* gb  = (const float*)d_in[11];
  const float* gms = (const float*)d_in[12];

  float* out = (float*)d_out;
  float* hemb  = out;                          // [100000,128]
  float* flat  = out + 12800000;               // [256,128]
  float* o_ei  = out + 12832768;               // [2,1600000]
  float* o_ea  = out + 16032768;               // [1600000,8]
  float* o_b   = out + 28832768;               // [100000]

  // Scratch without relying on ws_size: agg lives temporarily in the
  // edge_attr output region (needs 6.4M floats <= 12.8M available); the
  // MLP runs fully in-place in the h_emb region (per-row dependency only,
  // tiles staged to LDS before writes). Passthrough copies run last.
  float* agg = o_ea;
  float* h   = hemb;

  hipMemsetAsync(agg, 0, (size_t)N_NODES * IN_F * sizeof(float), stream);
  k_scatter<<<(N_EDGES * 64) / 256, 256, 0, stream>>>(inputs, ei, ei + N_EDGES, agg);
  k_gemm1<<<N_NODES / 32, 256, 0, stream>>>(inputs, agg, W1, b1, h);
  k_gemm128<<<N_NODES / 32, 256, 0, stream>>>(h, W2, b2, h);
  k_gemm128<<<N_NODES / 32, 256, 0, stream>>>(h, W3, b3, hemb);
  k_norm<<<N_GRAPHS, 256, 0, stream>>>(hemb, batch, gms, gw, gb, flat);
  // passthrough copies (overwrite the agg scratch region last)
  k_copy_i2f<<<(2 * N_EDGES + 255) / 256, 256, 0, stream>>>(ei, o_ei, 2 * N_EDGES);
  k_copy_f4<<<(N_EDGES * 2 + 255) / 256, 256, 0, stream>>>((const float4*)eattr, (float4*)o_ea, N_EDGES * 2);
  k_copy_i2f<<<(N_NODES + 255) / 256, 256, 0, stream>>>(batch, o_b, N_NODES);
}

// Round 2
// 553.378 us; speedup vs baseline: 1.2379x; 1.2379x over previous
//
#include <hip/hip_runtime.h>
#include <math.h>

#define N_NODES 100000
#define N_EDGES 1600000
#define N_GRAPHS 256
#define IN_F 64
#define H_F 128
#define GN_EPS 1e-5f
#define PAD 64

// ---------------- bucket fill: csr[d*PAD + pos] = s ----------------
__global__ __launch_bounds__(256) void k_fill(
    const int* __restrict__ src, const int* __restrict__ dst,
    int* __restrict__ csr, int* __restrict__ cnt,
    int* __restrict__ ovfc, int* __restrict__ ovf) {
  int e = blockIdx.x * 256 + threadIdx.x;
  if (e >= N_EDGES) return;
  int s = src[e], d = dst[e];
  int pos = atomicAdd(&cnt[d], 1);
  if (pos < PAD) {
    csr[(size_t)d * PAD + pos] = s;
  } else {
    int o = atomicAdd(ovfc, 1);
    ovf[2 * o] = s;
    ovf[2 * o + 1] = d;
  }
}

// ---------------- gather: one wave per node, lane = feature ----------------
__global__ __launch_bounds__(256) void k_gather(
    const float* __restrict__ x, const int* __restrict__ csr,
    const int* __restrict__ cnt, float* __restrict__ agg) {
  int wid = (blockIdx.x * 256 + threadIdx.x) >> 6;  // node id
  int lane = threadIdx.x & 63;                      // feature id
  if (wid >= N_NODES) return;
  int deg = cnt[wid];
  if (deg > PAD) deg = PAD;
  int myE = csr[(size_t)wid * PAD + lane];          // up to 64 edge ids in one 256B read
  float sum = 0.f;
  for (int j = 0; j < deg; ++j) {
    int s = __shfl(myE, j);
    sum += x[(size_t)s * IN_F + lane];
  }
  agg[(size_t)wid * IN_F + lane] = sum;
}

// ---------------- overflow cleanup (deg > PAD edges; expected empty) ----------------
__global__ __launch_bounds__(256) void k_ovf(
    const int* __restrict__ ovf, const int* __restrict__ ovfc,
    const float* __restrict__ x, float* __restrict__ agg) {
  int n = *ovfc;
  for (int idx = blockIdx.x * 256 + threadIdx.x; idx < n * 64; idx += gridDim.x * 256) {
    int o = idx >> 6, f = idx & 63;
    int s = ovf[2 * o], d = ovf[2 * o + 1];
    unsafeAtomicAdd(&agg[(size_t)d * IN_F + f], x[(size_t)s * IN_F + f]);
  }
}

// ---------------- GEMM1: out = relu((x+agg) @ W1 + b1), K=64 ----------------
__global__ __launch_bounds__(256) void k_gemm1(
    const float* __restrict__ xin, const float* __restrict__ agg,
    const float* __restrict__ W, const float* __restrict__ bias,
    float* __restrict__ out) {
  __shared__ float xT[IN_F][36];     // transposed x tile [k][m]
  __shared__ float Ws[IN_F * H_F];   // 32 KB
  const int t = threadIdx.x;
  const int m0 = blockIdx.x * 32;
#pragma unroll
  for (int it = 0; it < 2; ++it) {
    int flat = (t + it * 256) * 4;          // [32][64] row-major
    int m = flat >> 6, k = flat & 63;
    float4 a = *(const float4*)&xin[(size_t)(m0 + m) * IN_F + k];
    float4 g = *(const float4*)&agg[(size_t)(m0 + m) * IN_F + k];
    xT[k + 0][m] = a.x + g.x;
    xT[k + 1][m] = a.y + g.y;
    xT[k + 2][m] = a.z + g.z;
    xT[k + 3][m] = a.w + g.w;
  }
#pragma unroll
  for (int it = 0; it < 8; ++it) {
    int flat = (t + it * 256) * 4;
    *(float4*)&Ws[flat] = *(const float4*)&W[flat];
  }
  __syncthreads();
  const int tm0 = (t >> 5) * 4, tn0 = (t & 31) * 4;
  float acc[4][4] = {};
#pragma unroll 4
  for (int k = 0; k < IN_F; ++k) {
    float4 a = *(const float4*)&xT[k][tm0];
    float4 b = *(const float4*)&Ws[k * H_F + tn0];
    acc[0][0] += a.x * b.x; acc[0][1] += a.x * b.y; acc[0][2] += a.x * b.z; acc[0][3] += a.x * b.w;
    acc[1][0] += a.y * b.x; acc[1][1] += a.y * b.y; acc[1][2] += a.y * b.z; acc[1][3] += a.y * b.w;
    acc[2][0] += a.z * b.x; acc[2][1] += a.z * b.y; acc[2][2] += a.z * b.z; acc[2][3] += a.z * b.w;
    acc[3][0] += a.w * b.x; acc[3][1] += a.w * b.y; acc[3][2] += a.w * b.z; acc[3][3] += a.w * b.w;
  }
  float4 bv = *(const float4*)&bias[tn0];
#pragma unroll
  for (int i = 0; i < 4; ++i) {
    float4 r;
    r.x = fmaxf(acc[i][0] + bv.x, 0.f);
    r.y = fmaxf(acc[i][1] + bv.y, 0.f);
    r.z = fmaxf(acc[i][2] + bv.z, 0.f);
    r.w = fmaxf(acc[i][3] + bv.w, 0.f);
    *(float4*)&out[(size_t)(m0 + tm0 + i) * H_F + tn0] = r;
  }
}

// ---------------- GEMM (K=128): out = relu(in @ W + b); in-place safe ----------------
__global__ __launch_bounds__(256) void k_gemm128(
    const float* __restrict__ in, const float* __restrict__ W,
    const float* __restrict__ bias, float* __restrict__ out) {
  __shared__ float xT[H_F][36];     // 18 KB
  __shared__ float Ws[64 * H_F];    // 32 KB (half of W at a time)
  const int t = threadIdx.x;
  const int m0 = blockIdx.x * 32;
#pragma unroll
  for (int it = 0; it < 4; ++it) {
    int flat = (t + it * 256) * 4;          // [32][128] row-major
    int m = flat >> 7, k = flat & 127;
    float4 v = *(const float4*)&in[(size_t)(m0 + m) * H_F + k];
    xT[k + 0][m] = v.x; xT[k + 1][m] = v.y; xT[k + 2][m] = v.z; xT[k + 3][m] = v.w;
  }
  const int tm0 = (t >> 5) * 4, tn0 = (t & 31) * 4;
  float acc[4][4] = {};
  for (int kh = 0; kh < 2; ++kh) {
    __syncthreads();
#pragma unroll
    for (int it = 0; it < 8; ++it) {
      int flat = (t + it * 256) * 4;
      *(float4*)&Ws[flat] = *(const float4*)&W[kh * 64 * H_F + flat];
    }
    __syncthreads();
#pragma unroll 4
    for (int k = 0; k < 64; ++k) {
      float4 a = *(const float4*)&xT[kh * 64 + k][tm0];
      float4 b = *(const float4*)&Ws[k * H_F + tn0];
      acc[0][0] += a.x * b.x; acc[0][1] += a.x * b.y; acc[0][2] += a.x * b.z; acc[0][3] += a.x * b.w;
      acc[1][0] += a.y * b.x; acc[1][1] += a.y * b.y; acc[1][2] += a.y * b.z; acc[1][3] += a.y * b.w;
      acc[2][0] += a.z * b.x; acc[2][1] += a.z * b.y; acc[2][2] += a.z * b.z; acc[2][3] += a.z * b.w;
      acc[3][0] += a.w * b.x; acc[3][1] += a.w * b.y; acc[3][2] += a.w * b.z; acc[3][3] += a.w * b.w;
    }
  }
  float4 bv = *(const float4*)&bias[tn0];
#pragma unroll
  for (int i = 0; i < 4; ++i) {
    float4 r;
    r.x = fmaxf(acc[i][0] + bv.x, 0.f);
    r.y = fmaxf(acc[i][1] + bv.y, 0.f);
    r.z = fmaxf(acc[i][2] + bv.z, 0.f);
    r.w = fmaxf(acc[i][3] + bv.w, 0.f);
    *(float4*)&out[(size_t)(m0 + tm0 + i) * H_F + tn0] = r;
  }
}

// ---------------- GraphNorm + ReLU + segment-max, one block per graph ----------------
__global__ __launch_bounds__(256) void k_norm(
    float* __restrict__ h, const int* __restrict__ batch,
    const float* __restrict__ gms, const float* __restrict__ gw,
    const float* __restrict__ gb, float* __restrict__ flat) {
  const int g = blockIdx.x;
  const int t = threadIdx.x;
  __shared__ int sb[2];
  __shared__ float red[2][H_F];
  __shared__ float meanS[H_F], scaleS[H_F];
  if (t < 2) {
    int target = g + t;
    int lo = 0, hi = N_NODES;
    while (lo < hi) { int mid = (lo + hi) >> 1; if (batch[mid] < target) lo = mid + 1; else hi = mid; }
    sb[t] = lo;
  }
  __syncthreads();
  const int s = sb[0], e = sb[1];
  const int cnt = e - s;
  const int f = t & 127;
  const int half = t >> 7;
  if (cnt <= 0) {
    if (t < H_F) flat[(size_t)g * H_F + t] = -INFINITY;
    return;
  }
  float sum = 0.f;
  for (int n = s + half; n < e; n += 2) sum += h[(size_t)n * H_F + f];
  red[half][f] = sum;
  __syncthreads();
  if (half == 0) meanS[f] = (red[0][f] + red[1][f]) / (float)cnt * gms[f];
  __syncthreads();
  const float msc = meanS[f];
  float sq = 0.f;
  for (int n = s + half; n < e; n += 2) {
    float v = h[(size_t)n * H_F + f] - msc;
    sq += v * v;
  }
  red[half][f] = sq;
  __syncthreads();
  if (half == 0) {
    float var = (red[0][f] + red[1][f]) / (float)cnt;
    scaleS[f] = 1.0f / sqrtf(var + GN_EPS) * gw[f];
  }
  __syncthreads();
  const float sc = scaleS[f], bb = gb[f];
  float mx = -INFINITY;
  for (int n = s + half; n < e; n += 2) {
    size_t idx = (size_t)n * H_F + f;
    float v = (h[idx] - msc) * sc + bb;
    v = fmaxf(v, 0.f);
    h[idx] = v;
    mx = fmaxf(mx, v);
  }
  red[half][f] = mx;
  __syncthreads();
  if (half == 0) flat[(size_t)g * H_F + f] = fmaxf(red[0][f], red[1][f]);
}

// ---------------- passthrough copies ----------------
__global__ __launch_bounds__(256) void k_copy_i2f(const int* __restrict__ in,
                                                  float* __restrict__ out, int n) {
  int i = blockIdx.x * 256 + threadIdx.x;
  if (i < n) out[i] = (float)in[i];
}
__global__ __launch_bounds__(256) void k_copy_f4(const float4* __restrict__ in,
                                                 float4* __restrict__ out, int n4) {
  int i = blockIdx.x * 256 + threadIdx.x;
  if (i < n4) out[i] = in[i];
}

extern "C" void kernel_launch(void* const* d_in, const int* in_sizes, int n_in,
                              void* d_out, int out_size, void* d_ws, size_t ws_size,
                              hipStream_t stream) {
  const float* inputs = (const float*)d_in[0];
  const int*   ei     = (const int*)d_in[1];   // [2, N_EDGES]
  const int*   batch  = (const int*)d_in[2];   // [N_NODES]
  const float* eattr  = (const float*)d_in[3]; // [N_EDGES, 8]
  const float* W1 = (const float*)d_in[4];
  const float* b1 = (const float*)d_in[5];
  const float* W2 = (const float*)d_in[6];
  const float* b2 = (const float*)d_in[7];
  const float* W3 = (const float*)d_in[8];
  const float* b3 = (const float*)d_in[9];
  const float* gw  = (const float*)d_in[10];
  const float* gb  = (const float*)d_in[11];
  const float* gms = (const float*)d_in[12];

  float* out = (float*)d_out;
  float* hemb  = out;                          // [100000,128]
  float* flat  = out + 12800000;               // [256,128]
  float* o_ei  = out + 12832768;               // [2,1600000]
  float* o_ea  = out + 16032768;               // [1600000,8]
  float* o_b   = out + 28832768;               // [100000]

  // Scratch carved from output regions (overwritten by final copies):
  //   o_ea (12.8M floats): csr_pad (6.4M ints) + agg (6.4M floats)
  //   o_ei (3.2M floats):  cnt (100K ints) + ovf counter + ovf pairs
  int*   csr  = (int*)o_ea;                    // [N_NODES, PAD]
  float* agg  = o_ea + 6400000;                // [N_NODES, IN_F]
  int*   cnt  = (int*)o_ei;                    // [N_NODES]
  int*   ovfc = (int*)o_ei + 100000;           // [1]
  int*   ovf  = (int*)o_ei + 100032;           // pairs (s,d)

  hipMemsetAsync(cnt, 0, (N_NODES + 64) * sizeof(int), stream);
  k_fill<<<(N_EDGES + 255) / 256, 256, 0, stream>>>(ei, ei + N_EDGES, csr, cnt, ovfc, ovf);
  k_gather<<<(N_NODES * 64 + 255) / 256, 256, 0, stream>>>(inputs, csr, cnt, agg);
  k_ovf<<<16, 256, 0, stream>>>(ovf, ovfc, inputs, agg);
  k_gemm1<<<N_NODES / 32, 256, 0, stream>>>(inputs, agg, W1, b1, hemb);
  k_gemm128<<<N_NODES / 32, 256, 0, stream>>>(hemb, W2, b2, hemb);
  k_gemm128<<<N_NODES / 32, 256, 0, stream>>>(hemb, W3, b3, hemb);
  k_norm<<<N_GRAPHS, 256, 0, stream>>>(hemb, batch, gms, gw, gb, flat);
  // passthrough copies last (overwrite scratch regions)
  k_copy_i2f<<<(2 * N_EDGES + 255) / 256, 256, 0, stream>>>(ei, o_ei, 2 * N_EDGES);
  k_copy_f4<<<(N_EDGES * 2 + 255) / 256, 256, 0, stream>>>((const float4*)eattr, (float4*)o_ea, N_EDGES * 2);
  k_copy_i2f<<<(N_NODES + 255) / 256, 256, 0, stream>>>(batch, o_b, N_NODES);
}

// Round 3
// 419.390 us; speedup vs baseline: 1.6333x; 1.3195x over previous
//
#include <hip/hip_runtime.h>
#include <math.h>

#define N_NODES 100000
#define N_EDGES 1600000
#define N_GRAPHS 256
#define IN_F 64
#define H_F 128
#define GN_EPS 1e-5f
#define PAD 64

// ---------------- bucket fill: csr[d*PAD + pos] = s ----------------
__global__ __launch_bounds__(256) void k_fill(
    const int* __restrict__ src, const int* __restrict__ dst,
    int* __restrict__ csr, int* __restrict__ cnt,
    int* __restrict__ ovfc, int* __restrict__ ovf) {
  int e = blockIdx.x * 256 + threadIdx.x;
  if (e >= N_EDGES) return;
  int s = src[e], d = dst[e];
  int pos = atomicAdd(&cnt[d], 1);
  if (pos < PAD) {
    csr[(size_t)d * PAD + pos] = s;
  } else {
    int o = atomicAdd(ovfc, 1);
    ovf[2 * o] = s;
    ovf[2 * o + 1] = d;
  }
}

// ---------------- gather: one wave per node, lane = feature ----------------
__global__ __launch_bounds__(256) void k_gather(
    const float* __restrict__ x, const int* __restrict__ csr,
    const int* __restrict__ cnt, float* __restrict__ agg) {
  int wid = (blockIdx.x * 256 + threadIdx.x) >> 6;  // node id
  int lane = threadIdx.x & 63;                      // feature id
  if (wid >= N_NODES) return;
  int deg = cnt[wid];
  if (deg > PAD) deg = PAD;
  int myE = csr[(size_t)wid * PAD + lane];          // up to 64 edge ids in one 256B read
  float sum = 0.f;
  for (int j = 0; j < deg; ++j) {
    int s = __shfl(myE, j);
    sum += x[(size_t)s * IN_F + lane];
  }
  agg[(size_t)wid * IN_F + lane] = sum;
}

// ---------------- overflow cleanup (deg > PAD edges; expected empty) ----------------
__global__ __launch_bounds__(256) void k_ovf(
    const int* __restrict__ ovf, const int* __restrict__ ovfc,
    const float* __restrict__ x, float* __restrict__ agg) {
  int n = *ovfc;
  for (int idx = blockIdx.x * 256 + threadIdx.x; idx < n * 64; idx += gridDim.x * 256) {
    int o = idx >> 6, f = idx & 63;
    int s = ovf[2 * o], d = ovf[2 * o + 1];
    unsafeAtomicAdd(&agg[(size_t)d * IN_F + f], x[(size_t)s * IN_F + f]);
  }
}

// ---------------- GEMM1: out = relu((x+agg) @ W1 + b1), K=64 ----------------
__global__ __launch_bounds__(256) void k_gemm1(
    const float* __restrict__ xin, const float* __restrict__ agg,
    const float* __restrict__ W, const float* __restrict__ bias,
    float* __restrict__ out) {
  __shared__ __align__(16) float xT[IN_F][36];
  __shared__ __align__(16) float Ws[IN_F * H_F];   // 32 KB
  const int t = threadIdx.x;
  const int m0 = blockIdx.x * 32;
#pragma unroll
  for (int it = 0; it < 2; ++it) {
    int flat = (t + it * 256) * 4;          // [32][64] row-major
    int m = flat >> 6, k = flat & 63;
    float4 a = *(const float4*)&xin[(size_t)(m0 + m) * IN_F + k];
    float4 g = *(const float4*)&agg[(size_t)(m0 + m) * IN_F + k];
    xT[k + 0][m] = a.x + g.x;
    xT[k + 1][m] = a.y + g.y;
    xT[k + 2][m] = a.z + g.z;
    xT[k + 3][m] = a.w + g.w;
  }
#pragma unroll
  for (int it = 0; it < 8; ++it) {
    int flat = (t + it * 256) * 4;
    *(float4*)&Ws[flat] = *(const float4*)&W[flat];
  }
  __syncthreads();
  const int tm0 = (t >> 5) * 4, tn0 = (t & 31) * 4;
  float acc[4][4] = {};
#pragma unroll 4
  for (int k = 0; k < IN_F; ++k) {
    float4 a = *(const float4*)&xT[k][tm0];
    float4 b = *(const float4*)&Ws[k * H_F + tn0];
    acc[0][0] += a.x * b.x; acc[0][1] += a.x * b.y; acc[0][2] += a.x * b.z; acc[0][3] += a.x * b.w;
    acc[1][0] += a.y * b.x; acc[1][1] += a.y * b.y; acc[1][2] += a.y * b.z; acc[1][3] += a.y * b.w;
    acc[2][0] += a.z * b.x; acc[2][1] += a.z * b.y; acc[2][2] += a.z * b.z; acc[2][3] += a.z * b.w;
    acc[3][0] += a.w * b.x; acc[3][1] += a.w * b.y; acc[3][2] += a.w * b.z; acc[3][3] += a.w * b.w;
  }
  float4 bv = *(const float4*)&bias[tn0];
#pragma unroll
  for (int i = 0; i < 4; ++i) {
    float4 r;
    r.x = fmaxf(acc[i][0] + bv.x, 0.f);
    r.y = fmaxf(acc[i][1] + bv.y, 0.f);
    r.z = fmaxf(acc[i][2] + bv.z, 0.f);
    r.w = fmaxf(acc[i][3] + bv.w, 0.f);
    *(float4*)&out[(size_t)(m0 + tm0 + i) * H_F + tn0] = r;
  }
}

// ---------------- GEMM (K=128): out = relu(in @ W + b); in-place safe ----------------
__global__ __launch_bounds__(256) void k_gemm128(
    const float* __restrict__ in, const float* __restrict__ W,
    const float* __restrict__ bias, float* __restrict__ out) {
  __shared__ __align__(16) float xT[H_F][36];     // 18 KB
  __shared__ __align__(16) float Ws[64 * H_F];    // 32 KB
  const int t = threadIdx.x;
  const int m0 = blockIdx.x * 32;
#pragma unroll
  for (int it = 0; it < 4; ++it) {
    int flat = (t + it * 256) * 4;          // [32][128] row-major
    int m = flat >> 7, k = flat & 127;
    float4 v = *(const float4*)&in[(size_t)(m0 + m) * H_F + k];
    xT[k + 0][m] = v.x; xT[k + 1][m] = v.y; xT[k + 2][m] = v.z; xT[k + 3][m] = v.w;
  }
  const int tm0 = (t >> 5) * 4, tn0 = (t & 31) * 4;
  float acc[4][4] = {};
  for (int kh = 0; kh < 2; ++kh) {
    __syncthreads();
#pragma unroll
    for (int it = 0; it < 8; ++it) {
      int flat = (t + it * 256) * 4;
      *(float4*)&Ws[flat] = *(const float4*)&W[kh * 64 * H_F + flat];
    }
    __syncthreads();
#pragma unroll 4
    for (int k = 0; k < 64; ++k) {
      float4 a = *(const float4*)&xT[kh * 64 + k][tm0];
      float4 b = *(const float4*)&Ws[k * H_F + tn0];
      acc[0][0] += a.x * b.x; acc[0][1] += a.x * b.y; acc[0][2] += a.x * b.z; acc[0][3] += a.x * b.w;
      acc[1][0] += a.y * b.x; acc[1][1] += a.y * b.y; acc[1][2] += a.y * b.z; acc[1][3] += a.y * b.w;
      acc[2][0] += a.z * b.x; acc[2][1] += a.z * b.y; acc[2][2] += a.z * b.z; acc[2][3] += a.z * b.w;
      acc[3][0] += a.w * b.x; acc[3][1] += a.w * b.y; acc[3][2] += a.w * b.z; acc[3][3] += a.w * b.w;
    }
  }
  float4 bv = *(const float4*)&bias[tn0];
#pragma unroll
  for (int i = 0; i < 4; ++i) {
    float4 r;
    r.x = fmaxf(acc[i][0] + bv.x, 0.f);
    r.y = fmaxf(acc[i][1] + bv.y, 0.f);
    r.z = fmaxf(acc[i][2] + bv.z, 0.f);
    r.w = fmaxf(acc[i][3] + bv.w, 0.f);
    *(float4*)&out[(size_t)(m0 + tm0 + i) * H_F + tn0] = r;
  }
}

// ---- GEMM3 + fused GraphNorm statistics (sum, sumsq per graph per feature) ----
__global__ __launch_bounds__(256) void k_gemm128_stat(
    const float* __restrict__ in, const float* __restrict__ W,
    const float* __restrict__ bias, float* __restrict__ out,
    const int* __restrict__ batch, float* __restrict__ gsum,
    float* __restrict__ gsumsq) {
  __shared__ __align__(16) float xT[H_F][36];     // 18 KB (reused as reduction scratch)
  __shared__ __align__(16) float Ws[64 * H_F];    // 32 KB
  const int t = threadIdx.x;
  const int m0 = blockIdx.x * 32;
#pragma unroll
  for (int it = 0; it < 4; ++it) {
    int flat = (t + it * 256) * 4;
    int m = flat >> 7, k = flat & 127;
    float4 v = *(const float4*)&in[(size_t)(m0 + m) * H_F + k];
    xT[k + 0][m] = v.x; xT[k + 1][m] = v.y; xT[k + 2][m] = v.z; xT[k + 3][m] = v.w;
  }
  const int tm0 = (t >> 5) * 4, tn0 = (t & 31) * 4;
  float acc[4][4] = {};
  for (int kh = 0; kh < 2; ++kh) {
    __syncthreads();
#pragma unroll
    for (int it = 0; it < 8; ++it) {
      int flat = (t + it * 256) * 4;
      *(float4*)&Ws[flat] = *(const float4*)&W[kh * 64 * H_F + flat];
    }
    __syncthreads();
#pragma unroll 4
    for (int k = 0; k < 64; ++k) {
      float4 a = *(const float4*)&xT[kh * 64 + k][tm0];
      float4 b = *(const float4*)&Ws[k * H_F + tn0];
      acc[0][0] += a.x * b.x; acc[0][1] += a.x * b.y; acc[0][2] += a.x * b.z; acc[0][3] += a.x * b.w;
      acc[1][0] += a.y * b.x; acc[1][1] += a.y * b.y; acc[1][2] += a.y * b.z; acc[1][3] += a.y * b.w;
      acc[2][0] += a.z * b.x; acc[2][1] += a.z * b.y; acc[2][2] += a.z * b.z; acc[2][3] += a.z * b.w;
      acc[3][0] += a.w * b.x; acc[3][1] += a.w * b.y; acc[3][2] += a.w * b.z; acc[3][3] += a.w * b.w;
    }
  }
  float4 bv = *(const float4*)&bias[tn0];
  float4 rr[4];
#pragma unroll
  for (int i = 0; i < 4; ++i) {
    rr[i].x = fmaxf(acc[i][0] + bv.x, 0.f);
    rr[i].y = fmaxf(acc[i][1] + bv.y, 0.f);
    rr[i].z = fmaxf(acc[i][2] + bv.z, 0.f);
    rr[i].w = fmaxf(acc[i][3] + bv.w, 0.f);
    *(float4*)&out[(size_t)(m0 + tm0 + i) * H_F + tn0] = rr[i];
  }
  // ---- fused per-graph sum / sumsq ----
  const int glo = batch[m0];
  const int ghi = batch[m0 + 31];
  const int rg = t >> 5, fq = t & 31;
  if (glo == ghi) {                       // block fully inside one graph (common)
    float4 s = {0,0,0,0}, q = {0,0,0,0};
#pragma unroll
    for (int i = 0; i < 4; ++i) {
      s.x += rr[i].x; s.y += rr[i].y; s.z += rr[i].z; s.w += rr[i].w;
      q.x += rr[i].x * rr[i].x; q.y += rr[i].y * rr[i].y;
      q.z += rr[i].z * rr[i].z; q.w += rr[i].w * rr[i].w;
    }
    __syncthreads();                      // done reading xT; reuse as scratch
    float4* sred = (float4*)&xT[0][0];    // 8*32 float4 = 4 KB
    float4* qred = sred + 256;            // next 4 KB
    sred[rg * 32 + fq] = s;
    qred[rg * 32 + fq] = q;
    __syncthreads();
    if (rg == 0) {
      float4 S = {0,0,0,0}, Q = {0,0,0,0};
#pragma unroll
      for (int j = 0; j < 8; ++j) {
        float4 a = sred[j * 32 + fq], b = qred[j * 32 + fq];
        S.x += a.x; S.y += a.y; S.z += a.z; S.w += a.w;
        Q.x += b.x; Q.y += b.y; Q.z += b.z; Q.w += b.w;
      }
      float* ps = &gsum[(size_t)glo * H_F + fq * 4];
      float* pq = &gsumsq[(size_t)glo * H_F + fq * 4];
      unsafeAtomicAdd(ps + 0, S.x); unsafeAtomicAdd(ps + 1, S.y);
      unsafeAtomicAdd(ps + 2, S.z); unsafeAtomicAdd(ps + 3, S.w);
      unsafeAtomicAdd(pq + 0, Q.x); unsafeAtomicAdd(pq + 1, Q.y);
      unsafeAtomicAdd(pq + 2, Q.z); unsafeAtomicAdd(pq + 3, Q.w);
    }
  } else {                                // graph boundary inside block (rare)
    int gcur = batch[m0 + tm0];
    float4 s = {0,0,0,0}, q = {0,0,0,0};
#pragma unroll
    for (int i = 0; i < 4; ++i) {
      int g = batch[m0 + tm0 + i];
      if (g != gcur) {
        float* ps = &gsum[(size_t)gcur * H_F + tn0];
        float* pq = &gsumsq[(size_t)gcur * H_F + tn0];
        unsafeAtomicAdd(ps + 0, s.x); unsafeAtomicAdd(ps + 1, s.y);
        unsafeAtomicAdd(ps + 2, s.z); unsafeAtomicAdd(ps + 3, s.w);
        unsafeAtomicAdd(pq + 0, q.x); unsafeAtomicAdd(pq + 1, q.y);
        unsafeAtomicAdd(pq + 2, q.z); unsafeAtomicAdd(pq + 3, q.w);
        s = make_float4(0, 0, 0, 0); q = make_float4(0, 0, 0, 0);
        gcur = g;
      }
      s.x += rr[i].x; s.y += rr[i].y; s.z += rr[i].z; s.w += rr[i].w;
      q.x += rr[i].x * rr[i].x; q.y += rr[i].y * rr[i].y;
      q.z += rr[i].z * rr[i].z; q.w += rr[i].w * rr[i].w;
    }
    float* ps = &gsum[(size_t)gcur * H_F + tn0];
    float* pq = &gsumsq[(size_t)gcur * H_F + tn0];
    unsafeAtomicAdd(ps + 0, s.x); unsafeAtomicAdd(ps + 1, s.y);
    unsafeAtomicAdd(ps + 2, s.z); unsafeAtomicAdd(ps + 3, s.w);
    unsafeAtomicAdd(pq + 0, q.x); unsafeAtomicAdd(pq + 1, q.y);
    unsafeAtomicAdd(pq + 2, q.z); unsafeAtomicAdd(pq + 3, q.w);
  }
}

// ---- finalize: per (graph,feature) compute shift/scale; init flat = -INF ----
__global__ __launch_bounds__(128) void k_finalize(
    const int* __restrict__ batch, const float* __restrict__ gsum,
    const float* __restrict__ gsumsq, const float* __restrict__ gms,
    const float* __restrict__ gw, float* __restrict__ msc,
    float* __restrict__ scale, float* __restrict__ flat) {
  const int g = blockIdx.x;
  const int f = threadIdx.x;
  __shared__ int sb[2];
  if (f < 2) {
    int target = g + f;
    int lo = 0, hi = N_NODES;
    while (lo < hi) { int mid = (lo + hi) >> 1; if (batch[mid] < target) lo = mid + 1; else hi = mid; }
    sb[f] = lo;
  }
  __syncthreads();
  float c = fmaxf((float)(sb[1] - sb[0]), 1.0f);
  float mean = gsum[(size_t)g * H_F + f] / c;
  float ms = mean * gms[f];
  float var = gsumsq[(size_t)g * H_F + f] / c - 2.0f * ms * mean + ms * ms;
  var = fmaxf(var, 0.0f);
  msc[(size_t)g * H_F + f] = ms;
  scale[(size_t)g * H_F + f] = gw[f] * rsqrtf(var + GN_EPS);
  flat[(size_t)g * H_F + f] = -INFINITY;
}

// ---- apply: h = relu((h - msc)*scale + gb); flat = segment max ----
__global__ __launch_bounds__(256) void k_apply(
    float* __restrict__ h, const int* __restrict__ batch,
    const float* __restrict__ msc, const float* __restrict__ scale,
    const float* __restrict__ gb, float* __restrict__ flat) {
  const int t = threadIdx.x;
  const int rg = t >> 5, fq = t & 31;
  const int m0 = blockIdx.x * 32;
  const int r0 = m0 + rg * 4;
  const float4 bb = *(const float4*)&gb[fq * 4];
  const int glo = batch[m0], ghi = batch[m0 + 31];
  __shared__ __align__(16) float4 mred[8][32];
  if (glo == ghi) {
    const float4 m = *(const float4*)&msc[(size_t)glo * H_F + fq * 4];
    const float4 sc = *(const float4*)&scale[(size_t)glo * H_F + fq * 4];
    float4 mx = {-INFINITY, -INFINITY, -INFINITY, -INFINITY};
#pragma unroll
    for (int i = 0; i < 4; ++i) {
      size_t idx = (size_t)(r0 + i) * H_F + fq * 4;
      float4 v = *(const float4*)&h[idx];
      v.x = fmaxf((v.x - m.x) * sc.x + bb.x, 0.f);
      v.y = fmaxf((v.y - m.y) * sc.y + bb.y, 0.f);
      v.z = fmaxf((v.z - m.z) * sc.z + bb.z, 0.f);
      v.w = fmaxf((v.w - m.w) * sc.w + bb.w, 0.f);
      *(float4*)&h[idx] = v;
      mx.x = fmaxf(mx.x, v.x); mx.y = fmaxf(mx.y, v.y);
      mx.z = fmaxf(mx.z, v.z); mx.w = fmaxf(mx.w, v.w);
    }
    mred[rg][fq] = mx;
    __syncthreads();
    if (rg == 0) {
#pragma unroll
      for (int j = 1; j < 8; ++j) {
        float4 a = mred[j][fq];
        mx.x = fmaxf(mx.x, a.x); mx.y = fmaxf(mx.y, a.y);
        mx.z = fmaxf(mx.z, a.z); mx.w = fmaxf(mx.w, a.w);
      }
      int* pf = (int*)&flat[(size_t)glo * H_F + fq * 4];
      atomicMax(pf + 0, __float_as_int(mx.x));
      atomicMax(pf + 1, __float_as_int(mx.y));
      atomicMax(pf + 2, __float_as_int(mx.z));
      atomicMax(pf + 3, __float_as_int(mx.w));
    }
  } else {
    int gcur = batch[r0];
    float4 mm = *(const float4*)&msc[(size_t)gcur * H_F + fq * 4];
    float4 ss = *(const float4*)&scale[(size_t)gcur * H_F + fq * 4];
    float4 mx = {-INFINITY, -INFINITY, -INFINITY, -INFINITY};
#pragma unroll
    for (int i = 0; i < 4; ++i) {
      int g = batch[r0 + i];
      if (g != gcur) {
        int* pf = (int*)&flat[(size_t)gcur * H_F + fq * 4];
        atomicMax(pf + 0, __float_as_int(mx.x));
        atomicMax(pf + 1, __float_as_int(mx.y));
        atomicMax(pf + 2, __float_as_int(mx.z));
        atomicMax(pf + 3, __float_as_int(mx.w));
        mx = make_float4(-INFINITY, -INFINITY, -INFINITY, -INFINITY);
        gcur = g;
        mm = *(const float4*)&msc[(size_t)gcur * H_F + fq * 4];
        ss = *(const float4*)&scale[(size_t)gcur * H_F + fq * 4];
      }
      size_t idx = (size_t)(r0 + i) * H_F + fq * 4;
      float4 v = *(const float4*)&h[idx];
      v.x = fmaxf((v.x - mm.x) * ss.x + bb.x, 0.f);
      v.y = fmaxf((v.y - mm.y) * ss.y + bb.y, 0.f);
      v.z = fmaxf((v.z - mm.z) * ss.z + bb.z, 0.f);
      v.w = fmaxf((v.w - mm.w) * ss.w + bb.w, 0.f);
      *(float4*)&h[idx] = v;
      mx.x = fmaxf(mx.x, v.x); mx.y = fmaxf(mx.y, v.y);
      mx.z = fmaxf(mx.z, v.z); mx.w = fmaxf(mx.w, v.w);
    }
    int* pf = (int*)&flat[(size_t)gcur * H_F + fq * 4];
    atomicMax(pf + 0, __float_as_int(mx.x));
    atomicMax(pf + 1, __float_as_int(mx.y));
    atomicMax(pf + 2, __float_as_int(mx.z));
    atomicMax(pf + 3, __float_as_int(mx.w));
    __syncthreads();   // match barrier count of uniform path (block-uniform branch, but be safe)
  }
}

// ---------------- passthrough copies ----------------
__global__ __launch_bounds__(256) void k_copy_i2f4(const int4* __restrict__ in,
                                                   float4* __restrict__ out, int n4) {
  int i = blockIdx.x * 256 + threadIdx.x;
  if (i < n4) {
    int4 v = in[i];
    out[i] = make_float4((float)v.x, (float)v.y, (float)v.z, (float)v.w);
  }
}
__global__ __launch_bounds__(256) void k_copy_f4(const float4* __restrict__ in,
                                                 float4* __restrict__ out, int n4) {
  int i = blockIdx.x * 256 + threadIdx.x;
  if (i < n4) out[i] = in[i];
}

extern "C" void kernel_launch(void* const* d_in, const int* in_sizes, int n_in,
                              void* d_out, int out_size, void* d_ws, size_t ws_size,
                              hipStream_t stream) {
  const float* inputs = (const float*)d_in[0];
  const int*   ei     = (const int*)d_in[1];   // [2, N_EDGES]
  const int*   batch  = (const int*)d_in[2];   // [N_NODES]
  const float* eattr  = (const float*)d_in[3]; // [N_EDGES, 8]
  const float* W1 = (const float*)d_in[4];
  const float* b1 = (const float*)d_in[5];
  const float* W2 = (const float*)d_in[6];
  const float* b2 = (const float*)d_in[7];
  const float* W3 = (const float*)d_in[8];
  const float* b3 = (const float*)d_in[9];
  const float* gw  = (const float*)d_in[10];
  const float* gb  = (const float*)d_in[11];
  const float* gms = (const float*)d_in[12];

  float* out = (float*)d_out;
  float* hemb  = out;                          // [100000,128]
  float* flat  = out + 12800000;               // [256,128]
  float* o_ei  = out + 12832768;               // [2,1600000]
  float* o_ea  = out + 16032768;               // [1600000,8]
  float* o_b   = out + 28832768;               // [100000]

  // Scratch carved from output regions (overwritten by final copies):
  //   o_ea (12.8M floats): csr_pad (6.4M ints) + agg (6.4M floats)
  //   o_ei (3.2M floats):  cnt + ovf + gsum/gsumsq/msc/scale
  int*   csr   = (int*)o_ea;                   // [N_NODES, PAD]
  float* agg   = o_ea + 6400000;               // [N_NODES, IN_F]
  int*   cnt   = (int*)o_ei;                   // [N_NODES]
  int*   ovfc  = (int*)o_ei + 100000;          // [1]
  int*   ovf   = (int*)o_ei + 100032;          // pairs (s,d), tiny
  float* gsum  = o_ei + 200000;                // [256,128]
  float* gsumq = o_ei + 232768;                // [256,128]
  float* msc   = o_ei + 265536;                // [256,128]
  float* scl   = o_ei + 298304;                // [256,128]

  hipMemsetAsync(cnt, 0, (N_NODES + 64) * sizeof(int), stream);
  hipMemsetAsync(gsum, 0, 2 * N_GRAPHS * H_F * sizeof(float), stream);
  k_fill<<<(N_EDGES + 255) / 256, 256, 0, stream>>>(ei, ei + N_EDGES, csr, cnt, ovfc, ovf);
  k_gather<<<(N_NODES * 64 + 255) / 256, 256, 0, stream>>>(inputs, csr, cnt, agg);
  k_ovf<<<16, 256, 0, stream>>>(ovf, ovfc, inputs, agg);
  k_gemm1<<<N_NODES / 32, 256, 0, stream>>>(inputs, agg, W1, b1, hemb);
  k_gemm128<<<N_NODES / 32, 256, 0, stream>>>(hemb, W2, b2, hemb);
  k_gemm128_stat<<<N_NODES / 32, 256, 0, stream>>>(hemb, W3, b3, hemb, batch, gsum, gsumq);
  k_finalize<<<N_GRAPHS, 128, 0, stream>>>(batch, gsum, gsumq, gms, gw, msc, scl, flat);
  k_apply<<<N_NODES / 32, 256, 0, stream>>>(hemb, batch, msc, scl, gb, flat);
  // passthrough copies last (overwrite scratch regions)
  k_copy_i2f4<<<(2 * N_EDGES / 4 + 255) / 256, 256, 0, stream>>>((const int4*)ei, (float4*)o_ei, 2 * N_EDGES / 4);
  k_copy_f4<<<(N_EDGES * 2 + 255) / 256, 256, 0, stream>>>((const float4*)eattr, (float4*)o_ea, N_EDGES * 2);
  k_copy_i2f4<<<(N_NODES / 4 + 255) / 256, 256, 0, stream>>>((const int4*)batch, (float4*)o_b, N_NODES / 4);
}

// Round 4
// 396.909 us; speedup vs baseline: 1.7259x; 1.0566x over previous
//
#include <hip/hip_runtime.h>
#include <math.h>

#define N_NODES 100000
#define N_EDGES 1600000
#define N_GRAPHS 256
#define IN_F 64
#define H_F 128
#define GN_EPS 1e-5f
#define PAD 64
#define NBINS 8
#define LCAP 512
#define BINCAP (1 << 18)   // 256K entries/bin (expected 200K, +128 sigma)

// ---- phase A: LDS-staged radix partition of edges into 8 dst-range bins ----
__global__ __launch_bounds__(256) void k_bin(
    const int* __restrict__ src, const int* __restrict__ dst,
    unsigned long long* __restrict__ binBuf, int* __restrict__ gbc) {
  __shared__ unsigned long long ebuf[NBINS][LCAP];   // 32 KB
  __shared__ int lcnt[NBINS];
  __shared__ int lbase[NBINS];
  const int t = threadIdx.x;
  if (t < NBINS) lcnt[t] = 0;
  __syncthreads();
  for (int e0 = blockIdx.x * 256; e0 < N_EDGES; e0 += gridDim.x * 256) {
    int e = e0 + t;
    if (e < N_EDGES) {
      int s = src[e], d = dst[e];
      int b = d / 12500;                             // 0..7
      int p = atomicAdd(&lcnt[b], 1);                // < 512 by invariant
      ebuf[b][p] = ((unsigned long long)(unsigned)d << 32) | (unsigned)s;
    }
    __syncthreads();
    if (t < NBINS && lcnt[t] >= 256) lbase[t] = atomicAdd(&gbc[t], lcnt[t]);
    __syncthreads();
#pragma unroll
    for (int b = 0; b < NBINS; ++b) {
      int c = lcnt[b];
      if (c >= 256) {
        unsigned long long* gp = binBuf + (size_t)b * BINCAP + lbase[b];
        for (int i = t; i < c; i += 256) gp[i] = ebuf[b][i];
      }
    }
    __syncthreads();
    if (t < NBINS && lcnt[t] >= 256) lcnt[t] = 0;
    __syncthreads();
  }
  // drain (all remaining bins are < 256)
  if (t < NBINS && lcnt[t] > 0) lbase[t] = atomicAdd(&gbc[t], lcnt[t]);
  __syncthreads();
#pragma unroll
  for (int b = 0; b < NBINS; ++b) {
    int c = lcnt[b];
    if (c > 0) {
      unsigned long long* gp = binBuf + (size_t)b * BINCAP + lbase[b];
      for (int i = t; i < c; i += 256) gp[i] = ebuf[b][i];
    }
  }
}

// ---- phase B: bucket fill, bin-per-XCD (bid&7 under round-robin dispatch) ----
__global__ __launch_bounds__(256) void k_fill2(
    const unsigned long long* __restrict__ binBuf, const int* __restrict__ gbc,
    int* __restrict__ csr, int* __restrict__ cnt,
    int* __restrict__ ovfc, int* __restrict__ ovf) {
  const int b = blockIdx.x & 7;
  const int nb = gbc[b];
  const unsigned long long* buf = binBuf + (size_t)b * BINCAP;
  const int stride = (gridDim.x >> 3) * 256;
  for (int i = (blockIdx.x >> 3) * 256 + threadIdx.x; i < nb; i += stride) {
    unsigned long long pk = buf[i];
    int d = (int)(pk >> 32), s = (int)(pk & 0xffffffffu);
    int pos = atomicAdd(&cnt[d], 1);
    if (pos < PAD) {
      csr[(size_t)d * PAD + pos] = s;
    } else {
      int o = atomicAdd(ovfc, 1);
      ovf[2 * o] = s;
      ovf[2 * o + 1] = d;
    }
  }
}

// ---------------- gather: one wave per node, lane = feature ----------------
__global__ __launch_bounds__(256) void k_gather(
    const float* __restrict__ x, const int* __restrict__ csr,
    const int* __restrict__ cnt, float* __restrict__ agg) {
  int wid = (blockIdx.x * 256 + threadIdx.x) >> 6;  // node id
  int lane = threadIdx.x & 63;                      // feature id
  if (wid >= N_NODES) return;
  int deg = cnt[wid];
  if (deg > PAD) deg = PAD;
  int myE = csr[(size_t)wid * PAD + lane];          // 64 edge ids in one 256B read
  float sum = 0.f;
  for (int j = 0; j < deg; ++j) {
    int s = __shfl(myE, j);
    sum += x[(size_t)s * IN_F + lane];
  }
  agg[(size_t)wid * IN_F + lane] = sum;
}

// ---------------- overflow cleanup (deg > PAD edges; expected empty) ----------------
__global__ __launch_bounds__(256) void k_ovf(
    const int* __restrict__ ovf, const int* __restrict__ ovfc,
    const float* __restrict__ x, float* __restrict__ agg) {
  int n = *ovfc;
  for (int idx = blockIdx.x * 256 + threadIdx.x; idx < n * 64; idx += gridDim.x * 256) {
    int o = idx >> 6, f = idx & 63;
    int s = ovf[2 * o], d = ovf[2 * o + 1];
    unsafeAtomicAdd(&agg[(size_t)d * IN_F + f], x[(size_t)s * IN_F + f]);
  }
}

// ---------------- GEMM1: out = relu((x+agg) @ W1 + b1), K=64 ----------------
__global__ __launch_bounds__(256) void k_gemm1(
    const float* __restrict__ xin, const float* __restrict__ agg,
    const float* __restrict__ W, const float* __restrict__ bias,
    float* __restrict__ out) {
  __shared__ __align__(16) float xT[IN_F][36];
  __shared__ __align__(16) float Ws[IN_F * H_F];   // 32 KB
  const int t = threadIdx.x;
  const int m0 = blockIdx.x * 32;
#pragma unroll
  for (int it = 0; it < 2; ++it) {
    int flat = (t + it * 256) * 4;          // [32][64] row-major
    int m = flat >> 6, k = flat & 63;
    float4 a = *(const float4*)&xin[(size_t)(m0 + m) * IN_F + k];
    float4 g = *(const float4*)&agg[(size_t)(m0 + m) * IN_F + k];
    xT[k + 0][m] = a.x + g.x;
    xT[k + 1][m] = a.y + g.y;
    xT[k + 2][m] = a.z + g.z;
    xT[k + 3][m] = a.w + g.w;
  }
#pragma unroll
  for (int it = 0; it < 8; ++it) {
    int flat = (t + it * 256) * 4;
    *(float4*)&Ws[flat] = *(const float4*)&W[flat];
  }
  __syncthreads();
  const int tm0 = (t >> 5) * 4, tn0 = (t & 31) * 4;
  float acc[4][4] = {};
#pragma unroll 4
  for (int k = 0; k < IN_F; ++k) {
    float4 a = *(const float4*)&xT[k][tm0];
    float4 b = *(const float4*)&Ws[k * H_F + tn0];
    acc[0][0] += a.x * b.x; acc[0][1] += a.x * b.y; acc[0][2] += a.x * b.z; acc[0][3] += a.x * b.w;
    acc[1][0] += a.y * b.x; acc[1][1] += a.y * b.y; acc[1][2] += a.y * b.z; acc[1][3] += a.y * b.w;
    acc[2][0] += a.z * b.x; acc[2][1] += a.z * b.y; acc[2][2] += a.z * b.z; acc[2][3] += a.z * b.w;
    acc[3][0] += a.w * b.x; acc[3][1] += a.w * b.y; acc[3][2] += a.w * b.z; acc[3][3] += a.w * b.w;
  }
  float4 bv = *(const float4*)&bias[tn0];
#pragma unroll
  for (int i = 0; i < 4; ++i) {
    float4 r;
    r.x = fmaxf(acc[i][0] + bv.x, 0.f);
    r.y = fmaxf(acc[i][1] + bv.y, 0.f);
    r.z = fmaxf(acc[i][2] + bv.z, 0.f);
    r.w = fmaxf(acc[i][3] + bv.w, 0.f);
    *(float4*)&out[(size_t)(m0 + tm0 + i) * H_F + tn0] = r;
  }
}

// ---------------- GEMM (K=128): out = relu(in @ W + b); in-place safe ----------------
__global__ __launch_bounds__(256) void k_gemm128(
    const float* __restrict__ in, const float* __restrict__ W,
    const float* __restrict__ bias, float* __restrict__ out) {
  __shared__ __align__(16) float xT[H_F][36];     // 18 KB
  __shared__ __align__(16) float Ws[64 * H_F];    // 32 KB
  const int t = threadIdx.x;
  const int m0 = blockIdx.x * 32;
#pragma unroll
  for (int it = 0; it < 4; ++it) {
    int flat = (t + it * 256) * 4;          // [32][128] row-major
    int m = flat >> 7, k = flat & 127;
    float4 v = *(const float4*)&in[(size_t)(m0 + m) * H_F + k];
    xT[k + 0][m] = v.x; xT[k + 1][m] = v.y; xT[k + 2][m] = v.z; xT[k + 3][m] = v.w;
  }
  const int tm0 = (t >> 5) * 4, tn0 = (t & 31) * 4;
  float acc[4][4] = {};
  for (int kh = 0; kh < 2; ++kh) {
    __syncthreads();
#pragma unroll
    for (int it = 0; it < 8; ++it) {
      int flat = (t + it * 256) * 4;
      *(float4*)&Ws[flat] = *(const float4*)&W[kh * 64 * H_F + flat];
    }
    __syncthreads();
#pragma unroll 4
    for (int k = 0; k < 64; ++k) {
      float4 a = *(const float4*)&xT[kh * 64 + k][tm0];
      float4 b = *(const float4*)&Ws[k * H_F + tn0];
      acc[0][0] += a.x * b.x; acc[0][1] += a.x * b.y; acc[0][2] += a.x * b.z; acc[0][3] += a.x * b.w;
      acc[1][0] += a.y * b.x; acc[1][1] += a.y * b.y; acc[1][2] += a.y * b.z; acc[1][3] += a.y * b.w;
      acc[2][0] += a.z * b.x; acc[2][1] += a.z * b.y; acc[2][2] += a.z * b.z; acc[2][3] += a.z * b.w;
      acc[3][0] += a.w * b.x; acc[3][1] += a.w * b.y; acc[3][2] += a.w * b.z; acc[3][3] += a.w * b.w;
    }
  }
  float4 bv = *(const float4*)&bias[tn0];
#pragma unroll
  for (int i = 0; i < 4; ++i) {
    float4 r;
    r.x = fmaxf(acc[i][0] + bv.x, 0.f);
    r.y = fmaxf(acc[i][1] + bv.y, 0.f);
    r.z = fmaxf(acc[i][2] + bv.z, 0.f);
    r.w = fmaxf(acc[i][3] + bv.w, 0.f);
    *(float4*)&out[(size_t)(m0 + tm0 + i) * H_F + tn0] = r;
  }
}

// ---- GEMM3 + fused GraphNorm statistics (sum, sumsq per graph per feature) ----
__global__ __launch_bounds__(256) void k_gemm128_stat(
    const float* __restrict__ in, const float* __restrict__ W,
    const float* __restrict__ bias, float* __restrict__ out,
    const int* __restrict__ batch, float* __restrict__ gsum,
    float* __restrict__ gsumsq) {
  __shared__ __align__(16) float xT[H_F][36];     // reused as reduction scratch
  __shared__ __align__(16) float Ws[64 * H_F];
  const int t = threadIdx.x;
  const int m0 = blockIdx.x * 32;
#pragma unroll
  for (int it = 0; it < 4; ++it) {
    int flat = (t + it * 256) * 4;
    int m = flat >> 7, k = flat & 127;
    float4 v = *(const float4*)&in[(size_t)(m0 + m) * H_F + k];
    xT[k + 0][m] = v.x; xT[k + 1][m] = v.y; xT[k + 2][m] = v.z; xT[k + 3][m] = v.w;
  }
  const int tm0 = (t >> 5) * 4, tn0 = (t & 31) * 4;
  float acc[4][4] = {};
  for (int kh = 0; kh < 2; ++kh) {
    __syncthreads();
#pragma unroll
    for (int it = 0; it < 8; ++it) {
      int flat = (t + it * 256) * 4;
      *(float4*)&Ws[flat] = *(const float4*)&W[kh * 64 * H_F + flat];
    }
    __syncthreads();
#pragma unroll 4
    for (int k = 0; k < 64; ++k) {
      float4 a = *(const float4*)&xT[kh * 64 + k][tm0];
      float4 b = *(const float4*)&Ws[k * H_F + tn0];
      acc[0][0] += a.x * b.x; acc[0][1] += a.x * b.y; acc[0][2] += a.x * b.z; acc[0][3] += a.x * b.w;
      acc[1][0] += a.y * b.x; acc[1][1] += a.y * b.y; acc[1][2] += a.y * b.z; acc[1][3] += a.y * b.w;
      acc[2][0] += a.z * b.x; acc[2][1] += a.z * b.y; acc[2][2] += a.z * b.z; acc[2][3] += a.z * b.w;
      acc[3][0] += a.w * b.x; acc[3][1] += a.w * b.y; acc[3][2] += a.w * b.z; acc[3][3] += a.w * b.w;
    }
  }
  float4 bv = *(const float4*)&bias[tn0];
  float4 rr[4];
#pragma unroll
  for (int i = 0; i < 4; ++i) {
    rr[i].x = fmaxf(acc[i][0] + bv.x, 0.f);
    rr[i].y = fmaxf(acc[i][1] + bv.y, 0.f);
    rr[i].z = fmaxf(acc[i][2] + bv.z, 0.f);
    rr[i].w = fmaxf(acc[i][3] + bv.w, 0.f);
    *(float4*)&out[(size_t)(m0 + tm0 + i) * H_F + tn0] = rr[i];
  }
  const int glo = batch[m0];
  const int ghi = batch[m0 + 31];
  const int rg = t >> 5, fq = t & 31;
  if (glo == ghi) {
    float4 s = {0,0,0,0}, q = {0,0,0,0};
#pragma unroll
    for (int i = 0; i < 4; ++i) {
      s.x += rr[i].x; s.y += rr[i].y; s.z += rr[i].z; s.w += rr[i].w;
      q.x += rr[i].x * rr[i].x; q.y += rr[i].y * rr[i].y;
      q.z += rr[i].z * rr[i].z; q.w += rr[i].w * rr[i].w;
    }
    __syncthreads();
    float4* sred = (float4*)&xT[0][0];
    float4* qred = sred + 256;
    sred[rg * 32 + fq] = s;
    qred[rg * 32 + fq] = q;
    __syncthreads();
    if (rg == 0) {
      float4 S = {0,0,0,0}, Q = {0,0,0,0};
#pragma unroll
      for (int j = 0; j < 8; ++j) {
        float4 a = sred[j * 32 + fq], b = qred[j * 32 + fq];
        S.x += a.x; S.y += a.y; S.z += a.z; S.w += a.w;
        Q.x += b.x; Q.y += b.y; Q.z += b.z; Q.w += b.w;
      }
      float* ps = &gsum[(size_t)glo * H_F + fq * 4];
      float* pq = &gsumsq[(size_t)glo * H_F + fq * 4];
      unsafeAtomicAdd(ps + 0, S.x); unsafeAtomicAdd(ps + 1, S.y);
      unsafeAtomicAdd(ps + 2, S.z); unsafeAtomicAdd(ps + 3, S.w);
      unsafeAtomicAdd(pq + 0, Q.x); unsafeAtomicAdd(pq + 1, Q.y);
      unsafeAtomicAdd(pq + 2, Q.z); unsafeAtomicAdd(pq + 3, Q.w);
    }
  } else {
    int gcur = batch[m0 + tm0];
    float4 s = {0,0,0,0}, q = {0,0,0,0};
#pragma unroll
    for (int i = 0; i < 4; ++i) {
      int g = batch[m0 + tm0 + i];
      if (g != gcur) {
        float* ps = &gsum[(size_t)gcur * H_F + tn0];
        float* pq = &gsumsq[(size_t)gcur * H_F + tn0];
        unsafeAtomicAdd(ps + 0, s.x); unsafeAtomicAdd(ps + 1, s.y);
        unsafeAtomicAdd(ps + 2, s.z); unsafeAtomicAdd(ps + 3, s.w);
        unsafeAtomicAdd(pq + 0, q.x); unsafeAtomicAdd(pq + 1, q.y);
        unsafeAtomicAdd(pq + 2, q.z); unsafeAtomicAdd(pq + 3, q.w);
        s = make_float4(0, 0, 0, 0); q = make_float4(0, 0, 0, 0);
        gcur = g;
      }
      s.x += rr[i].x; s.y += rr[i].y; s.z += rr[i].z; s.w += rr[i].w;
      q.x += rr[i].x * rr[i].x; q.y += rr[i].y * rr[i].y;
      q.z += rr[i].z * rr[i].z; q.w += rr[i].w * rr[i].w;
    }
    float* ps = &gsum[(size_t)gcur * H_F + tn0];
    float* pq = &gsumsq[(size_t)gcur * H_F + tn0];
    unsafeAtomicAdd(ps + 0, s.x); unsafeAtomicAdd(ps + 1, s.y);
    unsafeAtomicAdd(ps + 2, s.z); unsafeAtomicAdd(ps + 3, s.w);
    unsafeAtomicAdd(pq + 0, q.x); unsafeAtomicAdd(pq + 1, q.y);
    unsafeAtomicAdd(pq + 2, q.z); unsafeAtomicAdd(pq + 3, q.w);
  }
}

// ---- finalize: per (graph,feature) compute shift/scale; init flat = -INF ----
__global__ __launch_bounds__(128) void k_finalize(
    const int* __restrict__ batch, const float* __restrict__ gsum,
    const float* __restrict__ gsumsq, const float* __restrict__ gms,
    const float* __restrict__ gw, float* __restrict__ msc,
    float* __restrict__ scale, float* __restrict__ flat) {
  const int g = blockIdx.x;
  const int f = threadIdx.x;
  __shared__ int sb[2];
  if (f < 2) {
    int target = g + f;
    int lo = 0, hi = N_NODES;
    while (lo < hi) { int mid = (lo + hi) >> 1; if (batch[mid] < target) lo = mid + 1; else hi = mid; }
    sb[f] = lo;
  }
  __syncthreads();
  float c = fmaxf((float)(sb[1] - sb[0]), 1.0f);
  float mean = gsum[(size_t)g * H_F + f] / c;
  float ms = mean * gms[f];
  float var = gsumsq[(size_t)g * H_F + f] / c - 2.0f * ms * mean + ms * ms;
  var = fmaxf(var, 0.0f);
  msc[(size_t)g * H_F + f] = ms;
  scale[(size_t)g * H_F + f] = gw[f] * rsqrtf(var + GN_EPS);
  flat[(size_t)g * H_F + f] = -INFINITY;
}

// ---- apply: h = relu((h - msc)*scale + gb); flat = segment max ----
__global__ __launch_bounds__(256) void k_apply(
    float* __restrict__ h, const int* __restrict__ batch,
    const float* __restrict__ msc, const float* __restrict__ scale,
    const float* __restrict__ gb, float* __restrict__ flat) {
  const int t = threadIdx.x;
  const int rg = t >> 5, fq = t & 31;
  const int m0 = blockIdx.x * 32;
  const int r0 = m0 + rg * 4;
  const float4 bb = *(const float4*)&gb[fq * 4];
  const int glo = batch[m0], ghi = batch[m0 + 31];
  __shared__ __align__(16) float4 mred[8][32];
  if (glo == ghi) {
    const float4 m = *(const float4*)&msc[(size_t)glo * H_F + fq * 4];
    const float4 sc = *(const float4*)&scale[(size_t)glo * H_F + fq * 4];
    float4 mx = {-INFINITY, -INFINITY, -INFINITY, -INFINITY};
#pragma unroll
    for (int i = 0; i < 4; ++i) {
      size_t idx = (size_t)(r0 + i) * H_F + fq * 4;
      float4 v = *(const float4*)&h[idx];
      v.x = fmaxf((v.x - m.x) * sc.x + bb.x, 0.f);
      v.y = fmaxf((v.y - m.y) * sc.y + bb.y, 0.f);
      v.z = fmaxf((v.z - m.z) * sc.z + bb.z, 0.f);
      v.w = fmaxf((v.w - m.w) * sc.w + bb.w, 0.f);
      *(float4*)&h[idx] = v;
      mx.x = fmaxf(mx.x, v.x); mx.y = fmaxf(mx.y, v.y);
      mx.z = fmaxf(mx.z, v.z); mx.w = fmaxf(mx.w, v.w);
    }
    mred[rg][fq] = mx;
    __syncthreads();
    if (rg == 0) {
#pragma unroll
      for (int j = 1; j < 8; ++j) {
        float4 a = mred[j][fq];
        mx.x = fmaxf(mx.x, a.x); mx.y = fmaxf(mx.y, a.y);
        mx.z = fmaxf(mx.z, a.z); mx.w = fmaxf(mx.w, a.w);
      }
      int* pf = (int*)&flat[(size_t)glo * H_F + fq * 4];
      atomicMax(pf + 0, __float_as_int(mx.x));
      atomicMax(pf + 1, __float_as_int(mx.y));
      atomicMax(pf + 2, __float_as_int(mx.z));
      atomicMax(pf + 3, __float_as_int(mx.w));
    }
  } else {
    int gcur = batch[r0];
    float4 mm = *(const float4*)&msc[(size_t)gcur * H_F + fq * 4];
    float4 ss = *(const float4*)&scale[(size_t)gcur * H_F + fq * 4];
    float4 mx = {-INFINITY, -INFINITY, -INFINITY, -INFINITY};
#pragma unroll
    for (int i = 0; i < 4; ++i) {
      int g = batch[r0 + i];
      if (g != gcur) {
        int* pf = (int*)&flat[(size_t)gcur * H_F + fq * 4];
        atomicMax(pf + 0, __float_as_int(mx.x));
        atomicMax(pf + 1, __float_as_int(mx.y));
        atomicMax(pf + 2, __float_as_int(mx.z));
        atomicMax(pf + 3, __float_as_int(mx.w));
        mx = make_float4(-INFINITY, -INFINITY, -INFINITY, -INFINITY);
        gcur = g;
        mm = *(const float4*)&msc[(size_t)gcur * H_F + fq * 4];
        ss = *(const float4*)&scale[(size_t)gcur * H_F + fq * 4];
      }
      size_t idx = (size_t)(r0 + i) * H_F + fq * 4;
      float4 v = *(const float4*)&h[idx];
      v.x = fmaxf((v.x - mm.x) * ss.x + bb.x, 0.f);
      v.y = fmaxf((v.y - mm.y) * ss.y + bb.y, 0.f);
      v.z = fmaxf((v.z - mm.z) * ss.z + bb.z, 0.f);
      v.w = fmaxf((v.w - mm.w) * ss.w + bb.w, 0.f);
      *(float4*)&h[idx] = v;
      mx.x = fmaxf(mx.x, v.x); mx.y = fmaxf(mx.y, v.y);
      mx.z = fmaxf(mx.z, v.z); mx.w = fmaxf(mx.w, v.w);
    }
    int* pf = (int*)&flat[(size_t)gcur * H_F + fq * 4];
    atomicMax(pf + 0, __float_as_int(mx.x));
    atomicMax(pf + 1, __float_as_int(mx.y));
    atomicMax(pf + 2, __float_as_int(mx.z));
    atomicMax(pf + 3, __float_as_int(mx.w));
    __syncthreads();
  }
}

// ---------------- passthrough copies ----------------
__global__ __launch_bounds__(256) void k_copy_i2f4(const int4* __restrict__ in,
                                                   float4* __restrict__ out, int n4) {
  int i = blockIdx.x * 256 + threadIdx.x;
  if (i < n4) {
    int4 v = in[i];
    out[i] = make_float4((float)v.x, (float)v.y, (float)v.z, (float)v.w);
  }
}
__global__ __launch_bounds__(256) void k_copy_f4(const float4* __restrict__ in,
                                                 float4* __restrict__ out, int n4) {
  int i = blockIdx.x * 256 + threadIdx.x;
  if (i < n4) out[i] = in[i];
}

extern "C" void kernel_launch(void* const* d_in, const int* in_sizes, int n_in,
                              void* d_out, int out_size, void* d_ws, size_t ws_size,
                              hipStream_t stream) {
  const float* inputs = (const float*)d_in[0];
  const int*   ei     = (const int*)d_in[1];   // [2, N_EDGES]
  const int*   batch  = (const int*)d_in[2];   // [N_NODES]
  const float* eattr  = (const float*)d_in[3]; // [N_EDGES, 8]
  const float* W1 = (const float*)d_in[4];
  const float* b1 = (const float*)d_in[5];
  const float* W2 = (const float*)d_in[6];
  const float* b2 = (const float*)d_in[7];
  const float* W3 = (const float*)d_in[8];
  const float* b3 = (const float*)d_in[9];
  const float* gw  = (const float*)d_in[10];
  const float* gb  = (const float*)d_in[11];
  const float* gms = (const float*)d_in[12];

  float* out = (float*)d_out;
  float* hemb  = out;                          // [100000,128]
  float* flat  = out + 12800000;               // [256,128]
  float* o_ei  = out + 12832768;               // [2,1600000]
  float* o_ea  = out + 16032768;               // [1600000,8]
  float* o_b   = out + 28832768;               // [100000]

  // Scratch carved from output regions (all dead before the final copies):
  //   hemb (12.8M floats): binBuf [8][256K] u64 = 16 MB (free until k_gemm1)
  //   o_ea (12.8M floats): csr (6.4M ints) + agg (6.4M floats)
  //   o_ei (3.2M floats):  cnt + gbc + ovfc/ovf + gsum/gsumsq/msc/scale
  unsigned long long* binBuf = (unsigned long long*)hemb;
  int*   csr   = (int*)o_ea;                   // [N_NODES, PAD]
  float* agg   = o_ea + 6400000;               // [N_NODES, IN_F]
  int*   cnt   = (int*)o_ei;                   // [N_NODES]
  int*   ovfc  = (int*)o_ei + 100000;          // [1]
  int*   gbc   = (int*)o_ei + 100008;          // [8]
  int*   ovf   = (int*)o_ei + 100032;          // pairs (s,d), tiny
  float* gsum  = o_ei + 200000;                // [256,128]
  float* gsumq = o_ei + 232768;                // [256,128]
  float* msc   = o_ei + 265536;                // [256,128]
  float* scl   = o_ei + 298304;                // [256,128]

  hipMemsetAsync(cnt, 0, (N_NODES + 64) * sizeof(int), stream);   // covers ovfc+gbc
  hipMemsetAsync(gsum, 0, 2 * N_GRAPHS * H_F * sizeof(float), stream);
  k_bin<<<512, 256, 0, stream>>>(ei, ei + N_EDGES, binBuf, gbc);
  k_fill2<<<8 * 160, 256, 0, stream>>>(binBuf, gbc, csr, cnt, ovfc, ovf);
  k_gather<<<(N_NODES * 64 + 255) / 256, 256, 0, stream>>>(inputs, csr, cnt, agg);
  k_ovf<<<16, 256, 0, stream>>>(ovf, ovfc, inputs, agg);
  k_gemm1<<<N_NODES / 32, 256, 0, stream>>>(inputs, agg, W1, b1, hemb);
  k_gemm128<<<N_NODES / 32, 256, 0, stream>>>(hemb, W2, b2, hemb);
  k_gemm128_stat<<<N_NODES / 32, 256, 0, stream>>>(hemb, W3, b3, hemb, batch, gsum, gsumq);
  k_finalize<<<N_GRAPHS, 128, 0, stream>>>(batch, gsum, gsumq, gms, gw, msc, scl, flat);
  k_apply<<<N_NODES / 32, 256, 0, stream>>>(hemb, batch, msc, scl, gb, flat);
  // passthrough copies last (overwrite scratch regions)
  k_copy_i2f4<<<(2 * N_EDGES / 4 + 255) / 256, 256, 0, stream>>>((const int4*)ei, (float4*)o_ei, 2 * N_EDGES / 4);
  k_copy_f4<<<(N_EDGES * 2 + 255) / 256, 256, 0, stream>>>((const float4*)eattr, (float4*)o_ea, N_EDGES * 2);
  k_copy_i2f4<<<(N_NODES / 4 + 255) / 256, 256, 0, stream>>>((const int4*)batch, (float4*)o_b, N_NODES / 4);
}

// Round 6
// 340.169 us; speedup vs baseline: 2.0137x; 1.1668x over previous
//
#include <hip/hip_runtime.h>
#include <math.h>

#define N_NODES 100000
#define N_EDGES 1600000
#define N_GRAPHS 256
#define IN_F 64
#define H_F 128
#define GN_EPS 1e-5f
#define PAD 64
#define NBINS 8
#define LCAP 512
#define BINCAP (1 << 18)   // 256K entries/bin (expected 200K)

__device__ __forceinline__ float bf2f(unsigned short u) {
  return __uint_as_float(((unsigned int)u) << 16);
}
__device__ __forceinline__ unsigned short f2bf(float f) {
  unsigned int u = __float_as_uint(f);
  u += 0x7FFFu + ((u >> 16) & 1u);   // round-to-nearest-even
  return (unsigned short)(u >> 16);
}

// ---- cast x to bf16 (RTNE) ----
__global__ __launch_bounds__(256) void k_cast(const float4* __restrict__ in,
                                              ushort4* __restrict__ out, int n4) {
  int i = blockIdx.x * 256 + threadIdx.x;
  if (i < n4) {
    float4 v = in[i];
    ushort4 o;
    o.x = f2bf(v.x); o.y = f2bf(v.y); o.z = f2bf(v.z); o.w = f2bf(v.w);
    out[i] = o;
  }
}

// ---- phase A: LDS-staged radix partition of edges into 8 dst-range bins ----
__global__ __launch_bounds__(256) void k_bin(
    const int* __restrict__ src, const int* __restrict__ dst,
    unsigned long long* __restrict__ binBuf, int* __restrict__ gbc) {
  __shared__ unsigned long long ebuf[NBINS][LCAP];   // 32 KB
  __shared__ int lcnt[NBINS];
  __shared__ int lbase[NBINS];
  const int t = threadIdx.x;
  if (t < NBINS) lcnt[t] = 0;
  __syncthreads();
  for (int e0 = blockIdx.x * 256; e0 < N_EDGES; e0 += gridDim.x * 256) {
    int e = e0 + t;
    if (e < N_EDGES) {
      int s = src[e], d = dst[e];
      int b = d / 12500;                             // 0..7
      int p = atomicAdd(&lcnt[b], 1);                // < 512 by invariant
      ebuf[b][p] = ((unsigned long long)(unsigned)d << 32) | (unsigned)s;
    }
    __syncthreads();
    if (t < NBINS && lcnt[t] >= 256) lbase[t] = atomicAdd(&gbc[t], lcnt[t]);
    __syncthreads();
#pragma unroll
    for (int b = 0; b < NBINS; ++b) {
      int c = lcnt[b];
      if (c >= 256) {
        unsigned long long* gp = binBuf + (size_t)b * BINCAP + lbase[b];
        for (int i = t; i < c; i += 256) gp[i] = ebuf[b][i];
      }
    }
    __syncthreads();
    if (t < NBINS && lcnt[t] >= 256) lcnt[t] = 0;
    __syncthreads();
  }
  if (t < NBINS && lcnt[t] > 0) lbase[t] = atomicAdd(&gbc[t], lcnt[t]);
  __syncthreads();
#pragma unroll
  for (int b = 0; b < NBINS; ++b) {
    int c = lcnt[b];
    if (c > 0) {
      unsigned long long* gp = binBuf + (size_t)b * BINCAP + lbase[b];
      for (int i = t; i < c; i += 256) gp[i] = ebuf[b][i];
    }
  }
}

// ---- phase B: bucket fill, bin-per-XCD (bid&7 under round-robin dispatch) ----
__global__ __launch_bounds__(256) void k_fill2(
    const unsigned long long* __restrict__ binBuf, const int* __restrict__ gbc,
    int* __restrict__ csr, int* __restrict__ cnt,
    int* __restrict__ ovfc, int* __restrict__ ovf) {
  const int b = blockIdx.x & 7;
  const int nb = gbc[b];
  const unsigned long long* buf = binBuf + (size_t)b * BINCAP;
  const int stride = (gridDim.x >> 3) * 256;
  for (int i = (blockIdx.x >> 3) * 256 + threadIdx.x; i < nb; i += stride) {
    unsigned long long pk = buf[i];
    int d = (int)(pk >> 32), s = (int)(pk & 0xffffffffu);
    int pos = atomicAdd(&cnt[d], 1);
    if (pos < PAD) {
      csr[(size_t)d * PAD + pos] = s;
    } else {
      int o = atomicAdd(ovfc, 1);
      ovf[2 * o] = s;
      ovf[2 * o + 1] = d;
    }
  }
}

// ---- gather (bf16 x): wave per node; 16-lane group per src row; 4 rows/iter ----
__global__ __launch_bounds__(256) void k_gather(
    const unsigned short* __restrict__ xh, const int* __restrict__ csr,
    const int* __restrict__ cnt, float* __restrict__ agg) {
  int wid = (blockIdx.x * 256 + threadIdx.x) >> 6;  // node id
  if (wid >= N_NODES) return;
  const int lane = threadIdx.x & 63;
  const int g = lane >> 4;        // group 0..3
  const int fl = lane & 15;       // feature quad
  int deg = cnt[wid];
  if (deg > PAD) deg = PAD;
  int myE = csr[(size_t)wid * PAD + lane];          // 64 edge ids, one 256B read
  float s0 = 0.f, s1 = 0.f, s2 = 0.f, s3 = 0.f;
  int j = g;
  for (; j + 4 < deg; j += 8) {                     // 2 loads in flight
    int sA = __shfl(myE, j);
    int sB = __shfl(myE, j + 4);
    ushort4 a = *(const ushort4*)&xh[(size_t)sA * IN_F + fl * 4];
    ushort4 b = *(const ushort4*)&xh[(size_t)sB * IN_F + fl * 4];
    s0 += bf2f(a.x) + bf2f(b.x);
    s1 += bf2f(a.y) + bf2f(b.y);
    s2 += bf2f(a.z) + bf2f(b.z);
    s3 += bf2f(a.w) + bf2f(b.w);
  }
  if (j < deg) {
    int sA = __shfl(myE, j);
    ushort4 a = *(const ushort4*)&xh[(size_t)sA * IN_F + fl * 4];
    s0 += bf2f(a.x); s1 += bf2f(a.y); s2 += bf2f(a.z); s3 += bf2f(a.w);
  }
  // reduce across the 4 groups (lanes ^16, ^32)
  s0 += __shfl_xor(s0, 16); s1 += __shfl_xor(s1, 16);
  s2 += __shfl_xor(s2, 16); s3 += __shfl_xor(s3, 16);
  s0 += __shfl_xor(s0, 32); s1 += __shfl_xor(s1, 32);
  s2 += __shfl_xor(s2, 32); s3 += __shfl_xor(s3, 32);
  if (g == 0) {
    float4 r = make_float4(s0, s1, s2, s3);
    *(float4*)&agg[(size_t)wid * IN_F + fl * 4] = r;
  }
}

// ---- overflow cleanup (deg > PAD edges; expected empty) ----
__global__ __launch_bounds__(256) void k_ovf(
    const int* __restrict__ ovf, const int* __restrict__ ovfc,
    const float* __restrict__ x, float* __restrict__ agg) {
  int n = *ovfc;
  for (int idx = blockIdx.x * 256 + threadIdx.x; idx < n * 64; idx += gridDim.x * 256) {
    int o = idx >> 6, f = idx & 63;
    int s = ovf[2 * o], d = ovf[2 * o + 1];
    unsafeAtomicAdd(&agg[(size_t)d * IN_F + f], x[(size_t)s * IN_F + f]);
  }
}

// ---------------- GEMM1: out = relu((x+agg) @ W1 + b1), K=64 ----------------
__global__ __launch_bounds__(256) void k_gemm1(
    const float* __restrict__ xin, const float* __restrict__ agg,
    const float* __restrict__ W, const float* __restrict__ bias,
    float* __restrict__ out) {
  __shared__ __align__(16) float xT[IN_F][36];
  __shared__ __align__(16) float Ws[IN_F * H_F];   // 32 KB
  const int t = threadIdx.x;
  const int m0 = blockIdx.x * 32;
#pragma unroll
  for (int it = 0; it < 2; ++it) {
    int flat = (t + it * 256) * 4;          // [32][64] row-major
    int m = flat >> 6, k = flat & 63;
    float4 a = *(const float4*)&xin[(size_t)(m0 + m) * IN_F + k];
    float4 g = *(const float4*)&agg[(size_t)(m0 + m) * IN_F + k];
    xT[k + 0][m] = a.x + g.x;
    xT[k + 1][m] = a.y + g.y;
    xT[k + 2][m] = a.z + g.z;
    xT[k + 3][m] = a.w + g.w;
  }
#pragma unroll
  for (int it = 0; it < 8; ++it) {
    int flat = (t + it * 256) * 4;
    *(float4*)&Ws[flat] = *(const float4*)&W[flat];
  }
  __syncthreads();
  const int tm0 = (t >> 5) * 4, tn0 = (t & 31) * 4;
  float acc[4][4] = {};
#pragma unroll 4
  for (int k = 0; k < IN_F; ++k) {
    float4 a = *(const float4*)&xT[k][tm0];
    float4 b = *(const float4*)&Ws[k * H_F + tn0];
    acc[0][0] += a.x * b.x; acc[0][1] += a.x * b.y; acc[0][2] += a.x * b.z; acc[0][3] += a.x * b.w;
    acc[1][0] += a.y * b.x; acc[1][1] += a.y * b.y; acc[1][2] += a.y * b.z; acc[1][3] += a.y * b.w;
    acc[2][0] += a.z * b.x; acc[2][1] += a.z * b.y; acc[2][2] += a.z * b.z; acc[2][3] += a.z * b.w;
    acc[3][0] += a.w * b.x; acc[3][1] += a.w * b.y; acc[3][2] += a.w * b.z; acc[3][3] += a.w * b.w;
  }
  float4 bv = *(const float4*)&bias[tn0];
#pragma unroll
  for (int i = 0; i < 4; ++i) {
    float4 r;
    r.x = fmaxf(acc[i][0] + bv.x, 0.f);
    r.y = fmaxf(acc[i][1] + bv.y, 0.f);
    r.z = fmaxf(acc[i][2] + bv.z, 0.f);
    r.w = fmaxf(acc[i][3] + bv.w, 0.f);
    *(float4*)&out[(size_t)(m0 + tm0 + i) * H_F + tn0] = r;
  }
}

// ---------------- GEMM (K=128): out = relu(in @ W + b); in-place safe ----------------
__global__ __launch_bounds__(256) void k_gemm128(
    const float* __restrict__ in, const float* __restrict__ W,
    const float* __restrict__ bias, float* __restrict__ out) {
  __shared__ __align__(16) float xT[H_F][36];     // 18 KB
  __shared__ __align__(16) float Ws[64 * H_F];    // 32 KB
  const int t = threadIdx.x;
  const int m0 = blockIdx.x * 32;
#pragma unroll
  for (int it = 0; it < 4; ++it) {
    int flat = (t + it * 256) * 4;          // [32][128] row-major
    int m = flat >> 7, k = flat & 127;
    float4 v = *(const float4*)&in[(size_t)(m0 + m) * H_F + k];
    xT[k + 0][m] = v.x; xT[k + 1][m] = v.y; xT[k + 2][m] = v.z; xT[k + 3][m] = v.w;
  }
  const int tm0 = (t >> 5) * 4, tn0 = (t & 31) * 4;
  float acc[4][4] = {};
  for (int kh = 0; kh < 2; ++kh) {
    __syncthreads();
#pragma unroll
    for (int it = 0; it < 8; ++it) {
      int flat = (t + it * 256) * 4;
      *(float4*)&Ws[flat] = *(const float4*)&W[kh * 64 * H_F + flat];
    }
    __syncthreads();
#pragma unroll 4
    for (int k = 0; k < 64; ++k) {
      float4 a = *(const float4*)&xT[kh * 64 + k][tm0];
      float4 b = *(const float4*)&Ws[k * H_F + tn0];
      acc[0][0] += a.x * b.x; acc[0][1] += a.x * b.y; acc[0][2] += a.x * b.z; acc[0][3] += a.x * b.w;
      acc[1][0] += a.y * b.x; acc[1][1] += a.y * b.y; acc[1][2] += a.y * b.z; acc[1][3] += a.y * b.w;
      acc[2][0] += a.z * b.x; acc[2][1] += a.z * b.y; acc[2][2] += a.z * b.z; acc[2][3] += a.z * b.w;
      acc[3][0] += a.w * b.x; acc[3][1] += a.w * b.y; acc[3][2] += a.w * b.z; acc[3][3] += a.w * b.w;
    }
  }
  float4 bv = *(const float4*)&bias[tn0];
#pragma unroll
  for (int i = 0; i < 4; ++i) {
    float4 r;
    r.x = fmaxf(acc[i][0] + bv.x, 0.f);
    r.y = fmaxf(acc[i][1] + bv.y, 0.f);
    r.z = fmaxf(acc[i][2] + bv.z, 0.f);
    r.w = fmaxf(acc[i][3] + bv.w, 0.f);
    *(float4*)&out[(size_t)(m0 + tm0 + i) * H_F + tn0] = r;
  }
}

// ---- GEMM3 + fused GraphNorm statistics (sum, sumsq per graph per feature) ----
__global__ __launch_bounds__(256) void k_gemm128_stat(
    const float* __restrict__ in, const float* __restrict__ W,
    const float* __restrict__ bias, float* __restrict__ out,
    const int* __restrict__ batch, float* __restrict__ gsum,
    float* __restrict__ gsumsq) {
  __shared__ __align__(16) float xT[H_F][36];     // reused as reduction scratch
  __shared__ __align__(16) float Ws[64 * H_F];
  const int t = threadIdx.x;
  const int m0 = blockIdx.x * 32;
#pragma unroll
  for (int it = 0; it < 4; ++it) {
    int flat = (t + it * 256) * 4;
    int m = flat >> 7, k = flat & 127;
    float4 v = *(const float4*)&in[(size_t)(m0 + m) * H_F + k];
    xT[k + 0][m] = v.x; xT[k + 1][m] = v.y; xT[k + 2][m] = v.z; xT[k + 3][m] = v.w;
  }
  const int tm0 = (t >> 5) * 4, tn0 = (t & 31) * 4;
  float acc[4][4] = {};
  for (int kh = 0; kh < 2; ++kh) {
    __syncthreads();
#pragma unroll
    for (int it = 0; it < 8; ++it) {
      int flat = (t + it * 256) * 4;
      *(float4*)&Ws[flat] = *(const float4*)&W[kh * 64 * H_F + flat];
    }
    __syncthreads();
#pragma unroll 4
    for (int k = 0; k < 64; ++k) {
      float4 a = *(const float4*)&xT[kh * 64 + k][tm0];
      float4 b = *(const float4*)&Ws[k * H_F + tn0];
      acc[0][0] += a.x * b.x; acc[0][1] += a.x * b.y; acc[0][2] += a.x * b.z; acc[0][3] += a.x * b.w;
      acc[1][0] += a.y * b.x; acc[1][1] += a.y * b.y; acc[1][2] += a.y * b.z; acc[1][3] += a.y * b.w;
      acc[2][0] += a.z * b.x; acc[2][1] += a.z * b.y; acc[2][2] += a.z * b.z; acc[2][3] += a.z * b.w;
      acc[3][0] += a.w * b.x; acc[3][1] += a.w * b.y; acc[3][2] += a.w * b.z; acc[3][3] += a.w * b.w;
    }
  }
  float4 bv = *(const float4*)&bias[tn0];
  float4 rr[4];
#pragma unroll
  for (int i = 0; i < 4; ++i) {
    rr[i].x = fmaxf(acc[i][0] + bv.x, 0.f);
    rr[i].y = fmaxf(acc[i][1] + bv.y, 0.f);
    rr[i].z = fmaxf(acc[i][2] + bv.z, 0.f);
    rr[i].w = fmaxf(acc[i][3] + bv.w, 0.f);
    *(float4*)&out[(size_t)(m0 + tm0 + i) * H_F + tn0] = rr[i];
  }
  const int glo = batch[m0];
  const int ghi = batch[m0 + 31];
  const int rg = t >> 5, fq = t & 31;
  if (glo == ghi) {
    float4 s = {0,0,0,0}, q = {0,0,0,0};
#pragma unroll
    for (int i = 0; i < 4; ++i) {
      s.x += rr[i].x; s.y += rr[i].y; s.z += rr[i].z; s.w += rr[i].w;
      q.x += rr[i].x * rr[i].x; q.y += rr[i].y * rr[i].y;
      q.z += rr[i].z * rr[i].z; q.w += rr[i].w * rr[i].w;
    }
    __syncthreads();
    float4* sred = (float4*)&xT[0][0];
    float4* qred = sred + 256;
    sred[rg * 32 + fq] = s;
    qred[rg * 32 + fq] = q;
    __syncthreads();
    if (rg == 0) {
      float4 S = {0,0,0,0}, Q = {0,0,0,0};
#pragma unroll
      for (int j = 0; j < 8; ++j) {
        float4 a = sred[j * 32 + fq], b = qred[j * 32 + fq];
        S.x += a.x; S.y += a.y; S.z += a.z; S.w += a.w;
        Q.x += b.x; Q.y += b.y; Q.z += b.z; Q.w += b.w;
      }
      float* ps = &gsum[(size_t)glo * H_F + fq * 4];
      float* pq = &gsumsq[(size_t)glo * H_F + fq * 4];
      unsafeAtomicAdd(ps + 0, S.x); unsafeAtomicAdd(ps + 1, S.y);
      unsafeAtomicAdd(ps + 2, S.z); unsafeAtomicAdd(ps + 3, S.w);
      unsafeAtomicAdd(pq + 0, Q.x); unsafeAtomicAdd(pq + 1, Q.y);
      unsafeAtomicAdd(pq + 2, Q.z); unsafeAtomicAdd(pq + 3, Q.w);
    }
  } else {
    int gcur = batch[m0 + tm0];
    float4 s = {0,0,0,0}, q = {0,0,0,0};
#pragma unroll
    for (int i = 0; i < 4; ++i) {
      int g = batch[m0 + tm0 + i];
      if (g != gcur) {
        float* ps = &gsum[(size_t)gcur * H_F + tn0];
        float* pq = &gsumsq[(size_t)gcur * H_F + tn0];
        unsafeAtomicAdd(ps + 0, s.x); unsafeAtomicAdd(ps + 1, s.y);
        unsafeAtomicAdd(ps + 2, s.z); unsafeAtomicAdd(ps + 3, s.w);
        unsafeAtomicAdd(pq + 0, q.x); unsafeAtomicAdd(pq + 1, q.y);
        unsafeAtomicAdd(pq + 2, q.z); unsafeAtomicAdd(pq + 3, q.w);
        s = make_float4(0, 0, 0, 0); q = make_float4(0, 0, 0, 0);
        gcur = g;
      }
      s.x += rr[i].x; s.y += rr[i].y; s.z += rr[i].z; s.w += rr[i].w;
      q.x += rr[i].x * rr[i].x; q.y += rr[i].y * rr[i].y;
      q.z += rr[i].z * rr[i].z; q.w += rr[i].w * rr[i].w;
    }
    float* ps = &gsum[(size_t)gcur * H_F + tn0];
    float* pq = &gsumsq[(size_t)gcur * H_F + tn0];
    unsafeAtomicAdd(ps + 0, s.x); unsafeAtomicAdd(ps + 1, s.y);
    unsafeAtomicAdd(ps + 2, s.z); unsafeAtomicAdd(ps + 3, s.w);
    unsafeAtomicAdd(pq + 0, q.x); unsafeAtomicAdd(pq + 1, q.y);
    unsafeAtomicAdd(pq + 2, q.z); unsafeAtomicAdd(pq + 3, q.w);
  }
}

// ---- finalize: per (graph,feature) compute shift/scale; init flat = -INF ----
__global__ __launch_bounds__(128) void k_finalize(
    const int* __restrict__ batch, const float* __restrict__ gsum,
    const float* __restrict__ gsumsq, const float* __restrict__ gms,
    const float* __restrict__ gw, float* __restrict__ msc,
    float* __restrict__ scale, float* __restrict__ flat) {
  const int g = blockIdx.x;
  const int f = threadIdx.x;
  __shared__ int sb[2];
  if (f < 2) {
    int target = g + f;
    int lo = 0, hi = N_NODES;
    while (lo < hi) { int mid = (lo + hi) >> 1; if (batch[mid] < target) lo = mid + 1; else hi = mid; }
    sb[f] = lo;
  }
  __syncthreads();
  float c = fmaxf((float)(sb[1] - sb[0]), 1.0f);
  float mean = gsum[(size_t)g * H_F + f] / c;
  float ms = mean * gms[f];
  float var = gsumsq[(size_t)g * H_F + f] / c - 2.0f * ms * mean + ms * ms;
  var = fmaxf(var, 0.0f);
  msc[(size_t)g * H_F + f] = ms;
  scale[(size_t)g * H_F + f] = gw[f] * rsqrtf(var + GN_EPS);
  flat[(size_t)g * H_F + f] = -INFINITY;
}

// ---- apply: h = relu((h - msc)*scale + gb); flat = segment max ----
__global__ __launch_bounds__(256) void k_apply(
    float* __restrict__ h, const int* __restrict__ batch,
    const float* __restrict__ msc, const float* __restrict__ scale,
    const float* __restrict__ gb, float* __restrict__ flat) {
  const int t = threadIdx.x;
  const int rg = t >> 5, fq = t & 31;
  const int m0 = blockIdx.x * 32;
  const int r0 = m0 + rg * 4;
  const float4 bb = *(const float4*)&gb[fq * 4];
  const int glo = batch[m0], ghi = batch[m0 + 31];
  __shared__ __align__(16) float4 mred[8][32];
  if (glo == ghi) {
    const float4 m = *(const float4*)&msc[(size_t)glo * H_F + fq * 4];
    const float4 sc = *(const float4*)&scale[(size_t)glo * H_F + fq * 4];
    float4 mx = {-INFINITY, -INFINITY, -INFINITY, -INFINITY};
#pragma unroll
    for (int i = 0; i < 4; ++i) {
      size_t idx = (size_t)(r0 + i) * H_F + fq * 4;
      float4 v = *(const float4*)&h[idx];
      v.x = fmaxf((v.x - m.x) * sc.x + bb.x, 0.f);
      v.y = fmaxf((v.y - m.y) * sc.y + bb.y, 0.f);
      v.z = fmaxf((v.z - m.z) * sc.z + bb.z, 0.f);
      v.w = fmaxf((v.w - m.w) * sc.w + bb.w, 0.f);
      *(float4*)&h[idx] = v;
      mx.x = fmaxf(mx.x, v.x); mx.y = fmaxf(mx.y, v.y);
      mx.z = fmaxf(mx.z, v.z); mx.w = fmaxf(mx.w, v.w);
    }
    mred[rg][fq] = mx;
    __syncthreads();
    if (rg == 0) {
#pragma unroll
      for (int j = 1; j < 8; ++j) {
        float4 a = mred[j][fq];
        mx.x = fmaxf(mx.x, a.x); mx.y = fmaxf(mx.y, a.y);
        mx.z = fmaxf(mx.z, a.z); mx.w = fmaxf(mx.w, a.w);
      }
      int* pf = (int*)&flat[(size_t)glo * H_F + fq * 4];
      atomicMax(pf + 0, __float_as_int(mx.x));
      atomicMax(pf + 1, __float_as_int(mx.y));
      atomicMax(pf + 2, __float_as_int(mx.z));
      atomicMax(pf + 3, __float_as_int(mx.w));
    }
  } else {
    int gcur = batch[r0];
    float4 mm = *(const float4*)&msc[(size_t)gcur * H_F + fq * 4];
    float4 ss = *(const float4*)&scale[(size_t)gcur * H_F + fq * 4];
    float4 mx = {-INFINITY, -INFINITY, -INFINITY, -INFINITY};
#pragma unroll
    for (int i = 0; i < 4; ++i) {
      int g = batch[r0 + i];
      if (g != gcur) {
        int* pf = (int*)&flat[(size_t)gcur * H_F + fq * 4];
        atomicMax(pf + 0, __float_as_int(mx.x));
        atomicMax(pf + 1, __float_as_int(mx.y));
        atomicMax(pf + 2, __float_as_int(mx.z));
        atomicMax(pf + 3, __float_as_int(mx.w));
        mx = make_float4(-INFINITY, -INFINITY, -INFINITY, -INFINITY);
        gcur = g;
        mm = *(const float4*)&msc[(size_t)gcur * H_F + fq * 4];
        ss = *(const float4*)&scale[(size_t)gcur * H_F + fq * 4];
      }
      size_t idx = (size_t)(r0 + i) * H_F + fq * 4;
      float4 v = *(const float4*)&h[idx];
      v.x = fmaxf((v.x - mm.x) * ss.x + bb.x, 0.f);
      v.y = fmaxf((v.y - mm.y) * ss.y + bb.y, 0.f);
      v.z = fmaxf((v.z - mm.z) * ss.z + bb.z, 0.f);
      v.w = fmaxf((v.w - mm.w) * ss.w + bb.w, 0.f);
      *(float4*)&h[idx] = v;
      mx.x = fmaxf(mx.x, v.x); mx.y = fmaxf(mx.y, v.y);
      mx.z = fmaxf(mx.z, v.z); mx.w = fmaxf(mx.w, v.w);
    }
    int* pf = (int*)&flat[(size_t)gcur * H_F + fq * 4];
    atomicMax(pf + 0, __float_as_int(mx.x));
    atomicMax(pf + 1, __float_as_int(mx.y));
    atomicMax(pf + 2, __float_as_int(mx.z));
    atomicMax(pf + 3, __float_as_int(mx.w));
    __syncthreads();
  }
}

// ---------------- passthrough copies ----------------
__global__ __launch_bounds__(256) void k_copy_i2f4(const int4* __restrict__ in,
                                                   float4* __restrict__ out, int n4) {
  int i = blockIdx.x * 256 + threadIdx.x;
  if (i < n4) {
    int4 v = in[i];
    out[i] = make_float4((float)v.x, (float)v.y, (float)v.z, (float)v.w);
  }
}
__global__ __launch_bounds__(256) void k_copy_f4(const float4* __restrict__ in,
                                                 float4* __restrict__ out, int n4) {
  int i = blockIdx.x * 256 + threadIdx.x;
  if (i < n4) out[i] = in[i];
}

extern "C" void kernel_launch(void* const* d_in, const int* in_sizes, int n_in,
                              void* d_out, int out_size, void* d_ws, size_t ws_size,
                              hipStream_t stream) {
  const float* inputs = (const float*)d_in[0];
  const int*   ei     = (const int*)d_in[1];   // [2, N_EDGES]
  const int*   batch  = (const int*)d_in[2];   // [N_NODES]
  const float* eattr  = (const float*)d_in[3]; // [N_EDGES, 8]
  const float* W1 = (const float*)d_in[4];
  const float* b1 = (const float*)d_in[5];
  const float* W2 = (const float*)d_in[6];
  const float* b2 = (const float*)d_in[7];
  const float* W3 = (const float*)d_in[8];
  const float* b3 = (const float*)d_in[9];
  const float* gw  = (const float*)d_in[10];
  const float* gb  = (const float*)d_in[11];
  const float* gms = (const float*)d_in[12];

  float* out = (float*)d_out;
  float* hemb  = out;                          // [100000,128]
  float* flat  = out + 12800000;               // [256,128]
  float* o_ei  = out + 12832768;               // [2,1600000]
  float* o_ea  = out + 16032768;               // [1600000,8]
  float* o_b   = out + 28832768;               // [100000]

  // Scratch carved from output regions (all dead before the final copies):
  //   hemb (51.2 MB): binBuf 16 MB @0, x_bf16 12.8 MB @16.8 MB
  //   o_ea (12.8M floats): csr (6.4M ints) + agg (6.4M floats)
  //   o_ei (3.2M floats):  cnt + gbc + ovfc/ovf + gsum/gsumsq/msc/scale
  unsigned long long* binBuf = (unsigned long long*)hemb;
  unsigned short* xh = (unsigned short*)(hemb + 4200000);
  int*   csr   = (int*)o_ea;                   // [N_NODES, PAD]
  float* agg   = o_ea + 6400000;               // [N_NODES, IN_F]
  int*   cnt   = (int*)o_ei;                   // [N_NODES]
  int*   ovfc  = (int*)o_ei + 100000;          // [1]
  int*   gbc   = (int*)o_ei + 100008;          // [8]
  int*   ovf   = (int*)o_ei + 100032;          // pairs (s,d), tiny
  float* gsum  = o_ei + 200000;                // [256,128]
  float* gsumq = o_ei + 232768;                // [256,128]
  float* msc   = o_ei + 265536;                // [256,128]
  float* scl   = o_ei + 298304;                // [256,128]

  hipMemsetAsync(cnt, 0, (N_NODES + 64) * sizeof(int), stream);   // covers ovfc+gbc
  hipMemsetAsync(gsum, 0, 2 * N_GRAPHS * H_F * sizeof(float), stream);
  k_cast<<<(N_NODES * IN_F / 4 + 255) / 256, 256, 0, stream>>>(
      (const float4*)inputs, (ushort4*)xh, N_NODES * IN_F / 4);
  k_bin<<<512, 256, 0, stream>>>(ei, ei + N_EDGES, binBuf, gbc);
  k_fill2<<<8 * 160, 256, 0, stream>>>(binBuf, gbc, csr, cnt, ovfc, ovf);
  k_gather<<<(N_NODES * 64 + 255) / 256, 256, 0, stream>>>(xh, csr, cnt, agg);
  k_ovf<<<16, 256, 0, stream>>>(ovf, ovfc, inputs, agg);
  k_gemm1<<<N_NODES / 32, 256, 0, stream>>>(inputs, agg, W1, b1, hemb);
  k_gemm128<<<N_NODES / 32, 256, 0, stream>>>(hemb, W2, b2, hemb);
  k_gemm128_stat<<<N_NODES / 32, 256, 0, stream>>>(hemb, W3, b3, hemb, batch, gsum, gsumq);
  k_finalize<<<N_GRAPHS, 128, 0, stream>>>(batch, gsum, gsumq, gms, gw, msc, scl, flat);
  k_apply<<<N_NODES / 32, 256, 0, stream>>>(hemb, batch, msc, scl, gb, flat);
  // passthrough copies last (overwrite scratch regions)
  k_copy_i2f4<<<(2 * N_EDGES / 4 + 255) / 256, 256, 0, stream>>>((const int4*)ei, (float4*)o_ei, 2 * N_EDGES / 4);
  k_copy_f4<<<(N_EDGES * 2 + 255) / 256, 256, 0, stream>>>((const float4*)eattr, (float4*)o_ea, N_EDGES * 2);
  k_copy_i2f4<<<(N_NODES / 4 + 255) / 256, 256, 0, stream>>>((const int4*)batch, (float4*)o_b, N_NODES / 4);
}